// Round 3
// baseline (762.319 us; speedup 1.0000x reference)
//
#include <hip/hip_runtime.h>

#define NN 20000
#define NE 320000
#define H  128
#define HH 64

__device__ __forceinline__ float lrelu(float v){ return fmaxf(v, 0.2f*v); }

// ---------------- node feature init ----------------
__global__ __launch_bounds__(256) void k_node_init(
    const float* __restrict__ shapes, const int* __restrict__ gid,
    const float* __restrict__ emb, const float* __restrict__ dimW,
    const float* __restrict__ dimb, float* __restrict__ x)
{
  int idx = blockIdx.x*256 + threadIdx.x;
  if (idx >= NN*H) return;
  int n = idx >> 7, j = idx & 127;
  float v;
  if (j < HH) v = shapes[n]*dimW[j] + dimb[j];
  else        v = emb[gid[n]*HH + (j-HH)];
  x[idx] = v;
}

// ---------------- CSR build ----------------
__global__ __launch_bounds__(256) void k_count(const int* __restrict__ dst, int* __restrict__ deg){
  int e = blockIdx.x*256 + threadIdx.x;
  if (e < NE) atomicAdd(&deg[dst[e]], 1);
}

__global__ __launch_bounds__(1024) void k_scan(const int* __restrict__ deg, int* __restrict__ off){
  __shared__ int ps[1024];
  int t = threadIdx.x;
  const int CH = (NN + 1023)/1024;   // 20
  int base = t*CH;
  int s = 0;
  for (int i=0;i<CH;i++){ int g=base+i; if (g<NN) s += deg[g]; }
  ps[t] = s; __syncthreads();
  for (int d=1; d<1024; d<<=1){
    int v = (t>=d) ? ps[t-d] : 0;
    __syncthreads();
    ps[t] += v;
    __syncthreads();
  }
  int run = (t==0) ? 0 : ps[t-1];
  for (int i=0;i<CH;i++){ int g=base+i; if (g<NN){ off[g]=run; run += deg[g]; } }
  if (t==1023) off[NN] = run;
}

__global__ __launch_bounds__(256) void k_fill(const int* __restrict__ src, const int* __restrict__ dst,
    const int* __restrict__ off, int* __restrict__ cur, int* __restrict__ csr){
  int e = blockIdx.x*256 + threadIdx.x;
  if (e < NE){
    int d = dst[e];
    int p = atomicAdd(&cur[d], 1);
    csr[off[d]+p] = src[e];
  }
}

// ---------------- SAGE mean aggregation (1 wave / node) ----------------
__global__ __launch_bounds__(256) void k_aggr(const float* __restrict__ x,
    const int* __restrict__ off, const int* __restrict__ csr, float* __restrict__ agg)
{
  int wid = (blockIdx.x*256 + threadIdx.x) >> 6;
  int lane = threadIdx.x & 63;
  if (wid >= NN) return;
  int b = off[wid], e = off[wid+1];
  float a0=0.f, a1=0.f;
  for (int i=b;i<e;i++){
    int s = csr[i];
    a0 += x[s*H + lane];
    a1 += x[s*H + 64 + lane];
  }
  float inv = 1.0f / fmaxf((float)(e-b), 1.0f);
  agg[wid*H + lane]      = a0*inv;
  agg[wid*H + 64 + lane] = a1*inv;
}

// ---------------- fused node GEMM: Y = [relu]( A@W1 [+ B@W2] [+ bias] ) ----------------
// 64-row tile, single 33.8KB LDS buffer reused for A then B.
template<bool TWO, bool RELU, bool BIAS>
__global__ __launch_bounds__(256) void k_gemm(
    const float* __restrict__ A, const float* __restrict__ W1,
    const float* __restrict__ B, const float* __restrict__ W2,
    const float* __restrict__ bias, float* __restrict__ Y, int M)
{
  __shared__ float T[64][132];
  int tid = threadIdx.x;
  int row0 = blockIdx.x*64;
  int eg = tid >> 4, cg = tid & 15;   // rows {eg+16r}, cols cg*8..cg*8+7

  float acc[4][8];
  #pragma unroll
  for (int r=0;r<4;r++)
    #pragma unroll
    for (int c=0;c<8;c++) acc[r][c]=0.f;

  const int npass = TWO ? 2 : 1;
  for (int pass=0; pass<npass; pass++){
    const float* S = (pass==0)? A  : B;
    const float* W = (pass==0)? W1 : W2;
    if (pass==1) __syncthreads();    // everyone done reading previous tile
    #pragma unroll
    for (int i=0;i<8;i++){
      int idx = tid + i*256;
      int r = idx >> 5, c4 = idx & 31;
      int row = row0 + r;
      float4 v = make_float4(0.f,0.f,0.f,0.f);
      if (row < M) v = *(const float4*)&S[row*H + c4*4];
      *(float4*)&T[r][c4*4] = v;
    }
    __syncthreads();
    for (int kb=0; kb<32; kb++){
      float wv[4][8];
      #pragma unroll
      for (int t=0;t<4;t++){
        float4 wa = *(const float4*)&W[(kb*4+t)*H + cg*8];
        float4 wb = *(const float4*)&W[(kb*4+t)*H + cg*8 + 4];
        wv[t][0]=wa.x; wv[t][1]=wa.y; wv[t][2]=wa.z; wv[t][3]=wa.w;
        wv[t][4]=wb.x; wv[t][5]=wb.y; wv[t][6]=wb.z; wv[t][7]=wb.w;
      }
      #pragma unroll
      for (int r=0;r<4;r++){
        float4 a = *(const float4*)&T[eg + r*16][kb*4];
        float av[4] = {a.x, a.y, a.z, a.w};
        #pragma unroll
        for (int t=0;t<4;t++)
          #pragma unroll
          for (int c=0;c<8;c++)
            acc[r][c] = fmaf(av[t], wv[t][c], acc[r][c]);
      }
    }
  }

  float bv[8];
  if constexpr (BIAS){
    float4 ba = *(const float4*)&bias[cg*8];
    float4 bb = *(const float4*)&bias[cg*8+4];
    bv[0]=ba.x; bv[1]=ba.y; bv[2]=ba.z; bv[3]=ba.w;
    bv[4]=bb.x; bv[5]=bb.y; bv[6]=bb.z; bv[7]=bb.w;
  } else {
    #pragma unroll
    for (int c=0;c<8;c++) bv[c]=0.f;
  }
  #pragma unroll
  for (int r=0;r<4;r++){
    int row = row0 + eg + r*16;
    if (row < M){
      float o[8];
      #pragma unroll
      for (int c=0;c<8;c++){
        float v = acc[r][c] + bv[c];
        o[c] = RELU ? fmaxf(v, 0.f) : v;
      }
      float4 o1 = make_float4(o[0],o[1],o[2],o[3]);
      float4 o2 = make_float4(o[4],o[5],o[6],o[7]);
      *(float4*)&Y[row*H + cg*8]     = o1;
      *(float4*)&Y[row*H + cg*8 + 4] = o2;
    }
  }
}

// ---------------- GAT per-node scalars ----------------
__global__ __launch_bounds__(256) void k_scal(const float* __restrict__ h,
    const float* __restrict__ asrc, const float* __restrict__ adst,
    float* __restrict__ hs, float* __restrict__ hd)
{
  int wid = (blockIdx.x*256 + threadIdx.x) >> 6;
  int lane = threadIdx.x & 63;
  if (wid >= NN) return;
  float h0 = h[wid*H + lane], h1 = h[wid*H + 64 + lane];
  float s = h0*asrc[lane] + h1*asrc[64+lane];
  float d = h0*adst[lane] + h1*adst[64+lane];
  #pragma unroll
  for (int o=32;o>0;o>>=1){ s += __shfl_down(s,o); d += __shfl_down(d,o); }
  if (lane==0){ hs[wid]=s; hd[wid]=d; }
}

// ---------------- GAT aggregation (1 wave / node, self-loop softmax) ----------------
__global__ __launch_bounds__(256) void k_gat(
    const float* __restrict__ h, const float* __restrict__ hs, const float* __restrict__ hd,
    const int* __restrict__ off, const int* __restrict__ csr,
    const float* __restrict__ bias, float* __restrict__ y)
{
  int wid = (blockIdx.x*256 + threadIdx.x) >> 6;
  int lane = threadIdx.x & 63;
  if (wid >= NN) return;
  int b = off[wid], e = off[wid+1];
  float hdv = hd[wid];
  float eself = lrelu(hs[wid] + hdv);
  float m = eself;
  for (int i=b;i<e;i++) m = fmaxf(m, lrelu(hs[csr[i]] + hdv));
  float z = expf(eself - m);
  float a0 = z * h[wid*H + lane];
  float a1 = z * h[wid*H + 64 + lane];
  for (int i=b;i<e;i++){
    int s = csr[i];
    float p = expf(lrelu(hs[s] + hdv) - m);
    z += p;
    a0 = fmaf(p, h[s*H + lane], a0);
    a1 = fmaf(p, h[s*H + 64 + lane], a1);
  }
  float inv = 1.0f / z;
  y[wid*H + lane]      = fmaxf(a0*inv + bias[lane], 0.f);
  y[wid*H + 64 + lane] = fmaxf(a1*inv + bias[64+lane], 0.f);
}

// ---------------- fused edge MLP: scores = (relu(relu((x[s]+x[d])@W1+b1)@W2+b2))@outW + outb ----------------
__global__ __launch_bounds__(256) void k_edge(
    const float* __restrict__ x, const int* __restrict__ src, const int* __restrict__ dst,
    const float* __restrict__ W1, const float* __restrict__ b1,
    const float* __restrict__ W2, const float* __restrict__ b2,
    const float* __restrict__ outW, const float* __restrict__ outb,
    float* __restrict__ out)
{
  __shared__ float T[64][132];
  __shared__ int se[64], de[64];
  int tid = threadIdx.x;
  int e0 = blockIdx.x*64;
  if (tid < 64){ se[tid] = src[e0+tid]; de[tid] = dst[e0+tid]; }
  __syncthreads();
  #pragma unroll
  for (int i=0;i<8;i++){
    int idx = tid + i*256;
    int r = idx >> 5, c4 = idx & 31;
    float4 a = *(const float4*)&x[se[r]*H + c4*4];
    float4 b = *(const float4*)&x[de[r]*H + c4*4];
    *(float4*)&T[r][c4*4] = make_float4(a.x+b.x, a.y+b.y, a.z+b.z, a.w+b.w);
  }
  __syncthreads();
  int eg = tid >> 4, cg = tid & 15;

  // ---- layer 1 ----
  float acc[4][8];
  #pragma unroll
  for (int r=0;r<4;r++)
    #pragma unroll
    for (int c=0;c<8;c++) acc[r][c]=0.f;
  for (int kb=0; kb<32; kb++){
    float wv[4][8];
    #pragma unroll
    for (int t=0;t<4;t++){
      float4 wa = *(const float4*)&W1[(kb*4+t)*H + cg*8];
      float4 wb = *(const float4*)&W1[(kb*4+t)*H + cg*8 + 4];
      wv[t][0]=wa.x; wv[t][1]=wa.y; wv[t][2]=wa.z; wv[t][3]=wa.w;
      wv[t][4]=wb.x; wv[t][5]=wb.y; wv[t][6]=wb.z; wv[t][7]=wb.w;
    }
    #pragma unroll
    for (int r=0;r<4;r++){
      float4 a = *(const float4*)&T[eg + r*16][kb*4];
      float av[4] = {a.x, a.y, a.z, a.w};
      #pragma unroll
      for (int t=0;t<4;t++)
        #pragma unroll
        for (int c=0;c<8;c++)
          acc[r][c] = fmaf(av[t], wv[t][c], acc[r][c]);
    }
  }
  float b1v[8];
  {
    float4 ba = *(const float4*)&b1[cg*8];
    float4 bb = *(const float4*)&b1[cg*8+4];
    b1v[0]=ba.x; b1v[1]=ba.y; b1v[2]=ba.z; b1v[3]=ba.w;
    b1v[4]=bb.x; b1v[5]=bb.y; b1v[6]=bb.z; b1v[7]=bb.w;
  }
  __syncthreads();  // all reads of T done before overwrite
  #pragma unroll
  for (int r=0;r<4;r++){
    float o[8];
    #pragma unroll
    for (int c=0;c<8;c++) o[c] = fmaxf(acc[r][c]+b1v[c], 0.f);
    *(float4*)&T[eg + r*16][cg*8]     = make_float4(o[0],o[1],o[2],o[3]);
    *(float4*)&T[eg + r*16][cg*8 + 4] = make_float4(o[4],o[5],o[6],o[7]);
  }
  __syncthreads();

  // ---- layer 2 + out ----
  float acc2[4][8];
  #pragma unroll
  for (int r=0;r<4;r++)
    #pragma unroll
    for (int c=0;c<8;c++) acc2[r][c]=0.f;
  for (int kb=0; kb<32; kb++){
    float wv[4][8];
    #pragma unroll
    for (int t=0;t<4;t++){
      float4 wa = *(const float4*)&W2[(kb*4+t)*H + cg*8];
      float4 wb = *(const float4*)&W2[(kb*4+t)*H + cg*8 + 4];
      wv[t][0]=wa.x; wv[t][1]=wa.y; wv[t][2]=wa.z; wv[t][3]=wa.w;
      wv[t][4]=wb.x; wv[t][5]=wb.y; wv[t][6]=wb.z; wv[t][7]=wb.w;
    }
    #pragma unroll
    for (int r=0;r<4;r++){
      float4 a = *(const float4*)&T[eg + r*16][kb*4];
      float av[4] = {a.x, a.y, a.z, a.w};
      #pragma unroll
      for (int t=0;t<4;t++)
        #pragma unroll
        for (int c=0;c<8;c++)
          acc2[r][c] = fmaf(av[t], wv[t][c], acc2[r][c]);
    }
  }
  float b2v[8], owv[8];
  {
    float4 ba = *(const float4*)&b2[cg*8];
    float4 bb = *(const float4*)&b2[cg*8+4];
    b2v[0]=ba.x; b2v[1]=ba.y; b2v[2]=ba.z; b2v[3]=ba.w;
    b2v[4]=bb.x; b2v[5]=bb.y; b2v[6]=bb.z; b2v[7]=bb.w;
    float4 oa = *(const float4*)&outW[cg*8];
    float4 ob = *(const float4*)&outW[cg*8+4];
    owv[0]=oa.x; owv[1]=oa.y; owv[2]=oa.z; owv[3]=oa.w;
    owv[4]=ob.x; owv[5]=ob.y; owv[6]=ob.z; owv[7]=ob.w;
  }
  float ob0 = outb[0];
  #pragma unroll
  for (int r=0;r<4;r++){
    float p = 0.f;
    #pragma unroll
    for (int c=0;c<8;c++) p = fmaf(fmaxf(acc2[r][c]+b2v[c],0.f), owv[c], p);
    #pragma unroll
    for (int o=8;o>0;o>>=1) p += __shfl_down(p, o, 16);
    if (cg==0) out[e0 + eg + r*16] = p + ob0;
  }
}

// ---------------- launch ----------------
extern "C" void kernel_launch(void* const* d_in, const int* in_sizes, int n_in,
                              void* d_out, int out_size, void* d_ws, size_t ws_size,
                              hipStream_t stream)
{
  const float* shapes   = (const float*)d_in[0];
  const int*   gate_ids = (const int*)  d_in[1];
  const int*   ei       = (const int*)  d_in[2];
  const float* emb      = (const float*)d_in[3];
  const float* dimW     = (const float*)d_in[4];
  const float* dimb     = (const float*)d_in[5];
  const float* sage_Wl  = (const float*)d_in[6];
  const float* sage_bl  = (const float*)d_in[7];
  const float* sage_Wr  = (const float*)d_in[8];
  const float* gat_W    = (const float*)d_in[9];
  const float* gat_asrc = (const float*)d_in[10];
  const float* gat_adst = (const float*)d_in[11];
  const float* gat_b    = (const float*)d_in[12];
  const float* edgeW    = (const float*)d_in[13];
  const float* edgeb    = (const float*)d_in[14];
  const float* outW     = (const float*)d_in[15];
  const float* outb     = (const float*)d_in[16];
  const int* src = ei;
  const int* dst = ei + NE;

  char* w = (char*)d_ws;
  auto alloc = [&](size_t bytes)->void* {
    void* p = (void*)w; w += (bytes + 255) & ~(size_t)255; return p;
  };
  float* xa   = (float*)alloc((size_t)NN*H*4);
  float* xb   = (float*)alloc((size_t)NN*H*4);
  float* agg  = (float*)alloc((size_t)NN*H*4);   // also reused as GAT h
  float* hs   = (float*)alloc((size_t)NN*4);
  float* hd   = (float*)alloc((size_t)NN*4);
  int*   deg  = (int*)alloc((size_t)NN*4);
  int*   off  = (int*)alloc((size_t)(NN+1)*4);
  int*   cur  = (int*)alloc((size_t)NN*4);
  int*   csr  = (int*)alloc((size_t)NE*4);

  hipMemsetAsync(deg, 0, (size_t)NN*4, stream);
  hipMemsetAsync(cur, 0, (size_t)NN*4, stream);

  k_node_init<<<(NN*H+255)/256, 256, 0, stream>>>(shapes, gate_ids, emb, dimW, dimb, xa);
  k_count<<<(NE+255)/256, 256, 0, stream>>>(dst, deg);
  k_scan<<<1, 1024, 0, stream>>>(deg, off);
  k_fill<<<(NE+255)/256, 256, 0, stream>>>(src, dst, off, cur, csr);

  float* xin = xa; float* xout = xb;
  const int gemm_blocks = (NN+63)/64;
  for (int i=0;i<3;i++){
    k_aggr<<<NN/4, 256, 0, stream>>>(xin, off, csr, agg);
    k_gemm<true,true,true><<<gemm_blocks, 256, 0, stream>>>(
        agg, sage_Wl + (size_t)i*H*H, xin, sage_Wr + (size_t)i*H*H,
        sage_bl + (size_t)i*H, xout, NN);
    float* t = xin; xin = xout; xout = t;
  }

  // GAT layer: h = x@W into agg buffer
  k_gemm<false,false,false><<<gemm_blocks, 256, 0, stream>>>(
      xin, gat_W, nullptr, nullptr, nullptr, agg, NN);
  k_scal<<<NN/4, 256, 0, stream>>>(agg, gat_asrc, gat_adst, hs, hd);
  k_gat<<<NN/4, 256, 0, stream>>>(agg, hs, hd, off, csr, gat_b, xout);
  { float* t = xin; xin = xout; xout = t; }

  k_edge<<<NE/64, 256, 0, stream>>>(xin, src, dst,
      edgeW, edgeb, edgeW + H*H, edgeb + H, outW, outb, (float*)d_out);
}

// Round 4
// 582.748 us; speedup vs baseline: 1.3081x; 1.3081x over previous
//
#include <hip/hip_runtime.h>

#define NN 20000
#define NE 320000
#define H  128
#define HH 64

typedef short bf16x8 __attribute__((ext_vector_type(8)));   // 8 bf16 = 4 VGPR
typedef float f32x4  __attribute__((ext_vector_type(4)));

__device__ __forceinline__ float lrelu(float v){ return fmaxf(v, 0.2f*v); }
__device__ __forceinline__ float as_f(unsigned u){ return __uint_as_float(u); }

// packed fp32->bf16 (RNE), 2 floats -> 1 u32 [lo16=cvt(a), hi16=cvt(b)]
__device__ __forceinline__ unsigned pk_bf16(float a, float b){
  unsigned r;
  asm("v_cvt_pk_bf16_f32 %0, %1, %2" : "=v"(r) : "v"(a), "v"(b));
  return r;
}

// ---------------- node feature init ----------------
__global__ __launch_bounds__(256) void k_node_init(
    const float* __restrict__ shapes, const int* __restrict__ gid,
    const float* __restrict__ emb, const float* __restrict__ dimW,
    const float* __restrict__ dimb, float* __restrict__ x)
{
  int idx = blockIdx.x*256 + threadIdx.x;
  if (idx >= NN*H) return;
  int n = idx >> 7, j = idx & 127;
  float v;
  if (j < HH) v = shapes[n]*dimW[j] + dimb[j];
  else        v = emb[gid[n]*HH + (j-HH)];
  x[idx] = v;
}

// ---------------- CSR build ----------------
__global__ __launch_bounds__(256) void k_count(const int* __restrict__ dst, int* __restrict__ deg){
  int e = blockIdx.x*256 + threadIdx.x;
  if (e < NE) atomicAdd(&deg[dst[e]], 1);
}

__global__ __launch_bounds__(1024) void k_scan(const int* __restrict__ deg, int* __restrict__ off){
  __shared__ int ps[1024];
  int t = threadIdx.x;
  const int CH = (NN + 1023)/1024;   // 20
  int base = t*CH;
  int s = 0;
  for (int i=0;i<CH;i++){ int g=base+i; if (g<NN) s += deg[g]; }
  ps[t] = s; __syncthreads();
  for (int d=1; d<1024; d<<=1){
    int v = (t>=d) ? ps[t-d] : 0;
    __syncthreads();
    ps[t] += v;
    __syncthreads();
  }
  int run = (t==0) ? 0 : ps[t-1];
  for (int i=0;i<CH;i++){ int g=base+i; if (g<NN){ off[g]=run; run += deg[g]; } }
  if (t==1023) off[NN] = run;
}

__global__ __launch_bounds__(256) void k_fill(const int* __restrict__ src, const int* __restrict__ dst,
    const int* __restrict__ off, int* __restrict__ cur, int* __restrict__ csr){
  int e = blockIdx.x*256 + threadIdx.x;
  if (e < NE){
    int d = dst[e];
    int p = atomicAdd(&cur[d], 1);
    csr[off[d]+p] = src[e];
  }
}

// ---------------- SAGE mean aggregation (1 wave / node) ----------------
__global__ __launch_bounds__(256) void k_aggr(const float* __restrict__ x,
    const int* __restrict__ off, const int* __restrict__ csr, float* __restrict__ agg)
{
  int wid = (blockIdx.x*256 + threadIdx.x) >> 6;
  int lane = threadIdx.x & 63;
  if (wid >= NN) return;
  int b = off[wid], e = off[wid+1];
  float a0=0.f, a1=0.f;
  for (int i=b;i<e;i++){
    int s = csr[i];
    a0 += x[s*H + lane];
    a1 += x[s*H + 64 + lane];
  }
  float inv = 1.0f / fmaxf((float)(e-b), 1.0f);
  agg[wid*H + lane]      = a0*inv;
  agg[wid*H + 64 + lane] = a1*inv;
}

// ---------------- fused node GEMM (fp32 VALU): Y = [relu]( A@W1 [+ B@W2] [+ bias] ) ----------------
template<bool TWO, bool RELU, bool BIAS>
__global__ __launch_bounds__(256) void k_gemm(
    const float* __restrict__ A, const float* __restrict__ W1,
    const float* __restrict__ B, const float* __restrict__ W2,
    const float* __restrict__ bias, float* __restrict__ Y, int M)
{
  __shared__ float T[64][132];
  int tid = threadIdx.x;
  int row0 = blockIdx.x*64;
  int eg = tid >> 4, cg = tid & 15;

  float acc[4][8];
  #pragma unroll
  for (int r=0;r<4;r++)
    #pragma unroll
    for (int c=0;c<8;c++) acc[r][c]=0.f;

  const int npass = TWO ? 2 : 1;
  for (int pass=0; pass<npass; pass++){
    const float* S = (pass==0)? A  : B;
    const float* W = (pass==0)? W1 : W2;
    if (pass==1) __syncthreads();
    #pragma unroll
    for (int i=0;i<8;i++){
      int idx = tid + i*256;
      int r = idx >> 5, c4 = idx & 31;
      int row = row0 + r;
      float4 v = make_float4(0.f,0.f,0.f,0.f);
      if (row < M) v = *(const float4*)&S[row*H + c4*4];
      *(float4*)&T[r][c4*4] = v;
    }
    __syncthreads();
    for (int kb=0; kb<32; kb++){
      float wv[4][8];
      #pragma unroll
      for (int t=0;t<4;t++){
        float4 wa = *(const float4*)&W[(kb*4+t)*H + cg*8];
        float4 wb = *(const float4*)&W[(kb*4+t)*H + cg*8 + 4];
        wv[t][0]=wa.x; wv[t][1]=wa.y; wv[t][2]=wa.z; wv[t][3]=wa.w;
        wv[t][4]=wb.x; wv[t][5]=wb.y; wv[t][6]=wb.z; wv[t][7]=wb.w;
      }
      #pragma unroll
      for (int r=0;r<4;r++){
        float4 a = *(const float4*)&T[eg + r*16][kb*4];
        float av[4] = {a.x, a.y, a.z, a.w};
        #pragma unroll
        for (int t=0;t<4;t++)
          #pragma unroll
          for (int c=0;c<8;c++)
            acc[r][c] = fmaf(av[t], wv[t][c], acc[r][c]);
      }
    }
  }

  float bv[8];
  if constexpr (BIAS){
    float4 ba = *(const float4*)&bias[cg*8];
    float4 bb = *(const float4*)&bias[cg*8+4];
    bv[0]=ba.x; bv[1]=ba.y; bv[2]=ba.z; bv[3]=ba.w;
    bv[4]=bb.x; bv[5]=bb.y; bv[6]=bb.z; bv[7]=bb.w;
  } else {
    #pragma unroll
    for (int c=0;c<8;c++) bv[c]=0.f;
  }
  #pragma unroll
  for (int r=0;r<4;r++){
    int row = row0 + eg + r*16;
    if (row < M){
      float o[8];
      #pragma unroll
      for (int c=0;c<8;c++){
        float v = acc[r][c] + bv[c];
        o[c] = RELU ? fmaxf(v, 0.f) : v;
      }
      *(float4*)&Y[row*H + cg*8]     = make_float4(o[0],o[1],o[2],o[3]);
      *(float4*)&Y[row*H + cg*8 + 4] = make_float4(o[4],o[5],o[6],o[7]);
    }
  }
}

// ---------------- GAT per-node scalars ----------------
__global__ __launch_bounds__(256) void k_scal(const float* __restrict__ h,
    const float* __restrict__ asrc, const float* __restrict__ adst,
    float* __restrict__ hs, float* __restrict__ hd)
{
  int wid = (blockIdx.x*256 + threadIdx.x) >> 6;
  int lane = threadIdx.x & 63;
  if (wid >= NN) return;
  float h0 = h[wid*H + lane], h1 = h[wid*H + 64 + lane];
  float s = h0*asrc[lane] + h1*asrc[64+lane];
  float d = h0*adst[lane] + h1*adst[64+lane];
  #pragma unroll
  for (int o=32;o>0;o>>=1){ s += __shfl_down(s,o); d += __shfl_down(d,o); }
  if (lane==0){ hs[wid]=s; hd[wid]=d; }
}

// ---------------- GAT aggregation ----------------
__global__ __launch_bounds__(256) void k_gat(
    const float* __restrict__ h, const float* __restrict__ hs, const float* __restrict__ hd,
    const int* __restrict__ off, const int* __restrict__ csr,
    const float* __restrict__ bias, float* __restrict__ y)
{
  int wid = (blockIdx.x*256 + threadIdx.x) >> 6;
  int lane = threadIdx.x & 63;
  if (wid >= NN) return;
  int b = off[wid], e = off[wid+1];
  float hdv = hd[wid];
  float eself = lrelu(hs[wid] + hdv);
  float m = eself;
  for (int i=b;i<e;i++) m = fmaxf(m, lrelu(hs[csr[i]] + hdv));
  float z = expf(eself - m);
  float a0 = z * h[wid*H + lane];
  float a1 = z * h[wid*H + 64 + lane];
  for (int i=b;i<e;i++){
    int s = csr[i];
    float p = expf(lrelu(hs[s] + hdv) - m);
    z += p;
    a0 = fmaf(p, h[s*H + lane], a0);
    a1 = fmaf(p, h[s*H + 64 + lane], a1);
  }
  float inv = 1.0f / z;
  y[wid*H + lane]      = fmaxf(a0*inv + bias[lane], 0.f);
  y[wid*H + 64 + lane] = fmaxf(a1*inv + bias[64+lane], 0.f);
}

// ================= MFMA edge MLP (bf16x2 split precision) =================
// Frag layout (16x16x32): lane l supplies A[m=l&15][k-slot g=l>>4, j=0..7],
// B[k-slot][n=l&15]; k = kc*32 + g*8 + j (same bijection both sides — safe).
// C (m89-verified): row=(l>>4)*4+r, col=l&15.
// LDS: A-hi/lo frag-linear [blk=rt*4+kc][lane][8] + W-half-hi/lo = 64 KB exact.

// stage one column-half of W (cols hf*64..+63) into frag-linear LDS, bf16-split
__device__ __forceinline__ void stage_W(const float* __restrict__ W, int hf, int tid,
                                        uint4* Wh, uint4* Wl)
{
  #pragma unroll
  for (int it=0; it<4; it++){
    int t  = tid + it*256;
    int s  = t & 63;
    int bw = (t >> 6) & 15;            // bw = ntl*4 + kc
    int row0 = (bw & 3)*32 + (s >> 4)*8;
    int col  = hf*64 + (bw >> 2)*16 + (s & 15);
    const float* p = W + row0*128 + col;
    float f[8];
    #pragma unroll
    for (int j=0;j<8;j++) f[j] = p[j*128];
    unsigned h0=pk_bf16(f[0],f[1]), h1=pk_bf16(f[2],f[3]),
             h2=pk_bf16(f[4],f[5]), h3=pk_bf16(f[6],f[7]);
    unsigned l0=pk_bf16(f[0]-as_f(h0<<16), f[1]-as_f(h0&0xffff0000u));
    unsigned l1=pk_bf16(f[2]-as_f(h1<<16), f[3]-as_f(h1&0xffff0000u));
    unsigned l2=pk_bf16(f[4]-as_f(h2<<16), f[5]-as_f(h2&0xffff0000u));
    unsigned l3=pk_bf16(f[6]-as_f(h3<<16), f[7]-as_f(h3&0xffff0000u));
    Wh[bw*64 + s] = make_uint4(h0,h1,h2,h3);
    Wl[bw*64 + s] = make_uint4(l0,l1,l2,l3);
  }
}

// one column-half of MFMAs: nt = HF*4+ntl, 3 MFMAs per (nt,kc) for bf16x2
template<int HF>
__device__ __forceinline__ void mfma_half(f32x4* acc, const bf16x8* ah, const bf16x8* al,
                                          const uint4* Wh, const uint4* Wl, int l)
{
  #pragma unroll
  for (int ntl=0; ntl<4; ntl++){
    f32x4 a = acc[HF*4 + ntl];
    #pragma unroll
    for (int kc=0; kc<4; kc++){
      bf16x8 bh = __builtin_bit_cast(bf16x8, Wh[(ntl*4+kc)*64 + l]);
      bf16x8 bl = __builtin_bit_cast(bf16x8, Wl[(ntl*4+kc)*64 + l]);
      a = __builtin_amdgcn_mfma_f32_16x16x32_bf16(ah[kc], bh, a, 0, 0, 0);
      a = __builtin_amdgcn_mfma_f32_16x16x32_bf16(ah[kc], bl, a, 0, 0, 0);
      a = __builtin_amdgcn_mfma_f32_16x16x32_bf16(al[kc], bh, a, 0, 0, 0);
    }
    acc[HF*4 + ntl] = a;
  }
}

__global__ __launch_bounds__(256) void k_edge_mfma(
    const float* __restrict__ x, const int* __restrict__ src, const int* __restrict__ dst,
    const float* __restrict__ W1, const float* __restrict__ b1,
    const float* __restrict__ W2, const float* __restrict__ b2,
    const float* __restrict__ outW, const float* __restrict__ outb,
    float* __restrict__ out)
{
  __shared__ uint4 Ah[1024], Al[1024], Wh[1024], Wl[1024];   // 64 KB exact
  const int tid = threadIdx.x;
  const int l = tid & 63, w = tid >> 6;
  const int e0 = blockIdx.x * 64;

  // ---- gather: E = x[src]+x[dst], split to bf16 hi/lo, frag-linear LDS ----
  // wave w supplies k-chunk kc=w for all 64 edges; lane l = edge row.
  {
    int e = e0 + l;
    int sn = src[e], dn = dst[e];
    const float4* ps = (const float4*)(x + (size_t)sn*H + w*32);
    const float4* pd = (const float4*)(x + (size_t)dn*H + w*32);
    float ev[32];
    #pragma unroll
    for (int q=0;q<8;q++){
      float4 a = ps[q], b = pd[q];
      ev[q*4+0]=a.x+b.x; ev[q*4+1]=a.y+b.y; ev[q*4+2]=a.z+b.z; ev[q*4+3]=a.w+b.w;
    }
    int blk = ((l>>4)*4 + w)*64;       // rt*4 + kc
    #pragma unroll
    for (int g=0; g<4; g++){
      unsigned hp[4], lp[4];
      #pragma unroll
      for (int q=0;q<4;q++){
        float f0 = ev[g*8+q*2], f1 = ev[g*8+q*2+1];
        unsigned h = pk_bf16(f0, f1);
        hp[q] = h;
        lp[q] = pk_bf16(f0 - as_f(h<<16), f1 - as_f(h & 0xffff0000u));
      }
      int ai = blk + (l&15) + 16*g;
      Ah[ai] = make_uint4(hp[0],hp[1],hp[2],hp[3]);
      Al[ai] = make_uint4(lp[0],lp[1],lp[2],lp[3]);
    }
  }
  stage_W(W1, 0, tid, Wh, Wl);
  __syncthreads();

  // ---- layer 1 ----
  bf16x8 ah[4], al[4];
  #pragma unroll
  for (int kc=0; kc<4; kc++){
    ah[kc] = __builtin_bit_cast(bf16x8, Ah[(w*4+kc)*64 + l]);
    al[kc] = __builtin_bit_cast(bf16x8, Al[(w*4+kc)*64 + l]);
  }
  f32x4 acc[8];
  #pragma unroll
  for (int i=0;i<8;i++) acc[i] = 0.f;

  mfma_half<0>(acc, ah, al, Wh, Wl, l);
  __syncthreads();
  stage_W(W1, 1, tid, Wh, Wl);
  __syncthreads();
  mfma_half<1>(acc, ah, al, Wh, Wl, l);

  // ---- epilogue 1: bias+relu, split, scatter into A2 frag layout (wave-local rows) ----
  {
    float b1v[8];
    #pragma unroll
    for (int nt=0;nt<8;nt++) b1v[nt] = b1[nt*16 + (l&15)];
    #pragma unroll
    for (int nt=0;nt<8;nt++){
      int b2blk = w*4 + (nt>>1);                       // rt2*4 + kc2
      int gp = (2*nt + ((l&15)>>3)) & 3;               // k-slot group of col
      #pragma unroll
      for (int r=0;r<4;r++){
        float v = fmaxf(acc[nt][r] + b1v[nt], 0.f);
        unsigned h = pk_bf16(v, v);
        unsigned lo = pk_bf16(v - as_f(h<<16), 0.f);
        int sp = (4*(l>>4) + r) + 16*gp;
        int off = (b2blk*64 + sp)*16 + (l&7)*2;
        *(short*)((char*)Ah + off) = (short)(h  & 0xffff);
        *(short*)((char*)Al + off) = (short)(lo & 0xffff);
      }
    }
  }
  __syncthreads();
  stage_W(W2, 0, tid, Wh, Wl);
  __syncthreads();

  // ---- layer 2 ----
  #pragma unroll
  for (int kc=0; kc<4; kc++){
    ah[kc] = __builtin_bit_cast(bf16x8, Ah[(w*4+kc)*64 + l]);
    al[kc] = __builtin_bit_cast(bf16x8, Al[(w*4+kc)*64 + l]);
  }
  f32x4 acc2[8];
  #pragma unroll
  for (int i=0;i<8;i++) acc2[i] = 0.f;

  mfma_half<0>(acc2, ah, al, Wh, Wl, l);
  __syncthreads();
  stage_W(W2, 1, tid, Wh, Wl);
  __syncthreads();
  mfma_half<1>(acc2, ah, al, Wh, Wl, l);

  // ---- epilogue 2: bias+relu, dot outW, reduce over 16 col-lanes ----
  {
    float b2v[8], owv[8];
    #pragma unroll
    for (int nt=0;nt<8;nt++){
      b2v[nt] = b2[nt*16 + (l&15)];
      owv[nt] = outW[nt*16 + (l&15)];
    }
    float ob = outb[0];
    #pragma unroll
    for (int r=0;r<4;r++){
      float p = 0.f;
      #pragma unroll
      for (int nt=0;nt<8;nt++)
        p = fmaf(fmaxf(acc2[nt][r] + b2v[nt], 0.f), owv[nt], p);
      #pragma unroll
      for (int m=1;m<16;m<<=1) p += __shfl_xor(p, m, 16);
      if ((l&15)==0) out[e0 + w*16 + (l>>4)*4 + r] = p + ob;
    }
  }
}

// ---------------- launch ----------------
extern "C" void kernel_launch(void* const* d_in, const int* in_sizes, int n_in,
                              void* d_out, int out_size, void* d_ws, size_t ws_size,
                              hipStream_t stream)
{
  const float* shapes   = (const float*)d_in[0];
  const int*   gate_ids = (const int*)  d_in[1];
  const int*   ei       = (const int*)  d_in[2];
  const float* emb      = (const float*)d_in[3];
  const float* dimW     = (const float*)d_in[4];
  const float* dimb     = (const float*)d_in[5];
  const float* sage_Wl  = (const float*)d_in[6];
  const float* sage_bl  = (const float*)d_in[7];
  const float* sage_Wr  = (const float*)d_in[8];
  const float* gat_W    = (const float*)d_in[9];
  const float* gat_asrc = (const float*)d_in[10];
  const float* gat_adst = (const float*)d_in[11];
  const float* gat_b    = (const float*)d_in[12];
  const float* edgeW    = (const float*)d_in[13];
  const float* edgeb    = (const float*)d_in[14];
  const float* outW     = (const float*)d_in[15];
  const float* outb     = (const float*)d_in[16];
  const int* src = ei;
  const int* dst = ei + NE;

  char* w = (char*)d_ws;
  auto alloc = [&](size_t bytes)->void* {
    void* p = (void*)w; w += (bytes + 255) & ~(size_t)255; return p;
  };
  float* xa   = (float*)alloc((size_t)NN*H*4);
  float* xb   = (float*)alloc((size_t)NN*H*4);
  float* agg  = (float*)alloc((size_t)NN*H*4);
  float* hs   = (float*)alloc((size_t)NN*4);
  float* hd   = (float*)alloc((size_t)NN*4);
  int*   deg  = (int*)alloc((size_t)NN*4);
  int*   off  = (int*)alloc((size_t)(NN+1)*4);
  int*   cur  = (int*)alloc((size_t)NN*4);
  int*   csr  = (int*)alloc((size_t)NE*4);

  hipMemsetAsync(deg, 0, (size_t)NN*4, stream);
  hipMemsetAsync(cur, 0, (size_t)NN*4, stream);

  k_node_init<<<(NN*H+255)/256, 256, 0, stream>>>(shapes, gate_ids, emb, dimW, dimb, xa);
  k_count<<<(NE+255)/256, 256, 0, stream>>>(dst, deg);
  k_scan<<<1, 1024, 0, stream>>>(deg, off);
  k_fill<<<(NE+255)/256, 256, 0, stream>>>(src, dst, off, cur, csr);

  float* xin = xa; float* xout = xb;
  const int gemm_blocks = (NN+63)/64;
  for (int i=0;i<3;i++){
    k_aggr<<<NN/4, 256, 0, stream>>>(xin, off, csr, agg);
    k_gemm<true,true,true><<<gemm_blocks, 256, 0, stream>>>(
        agg, sage_Wl + (size_t)i*H*H, xin, sage_Wr + (size_t)i*H*H,
        sage_bl + (size_t)i*H, xout, NN);
    float* t = xin; xin = xout; xout = t;
  }

  k_gemm<false,false,false><<<gemm_blocks, 256, 0, stream>>>(
      xin, gat_W, nullptr, nullptr, nullptr, agg, NN);
  k_scal<<<NN/4, 256, 0, stream>>>(agg, gat_asrc, gat_adst, hs, hd);
  k_gat<<<NN/4, 256, 0, stream>>>(agg, hs, hd, off, csr, gat_b, xout);
  { float* t = xin; xin = xout; xout = t; }

  k_edge_mfma<<<NE/64, 256, 0, stream>>>(xin, src, dst,
      edgeW, edgeb, edgeW + H*H, edgeb + H, outW, outb, (float*)d_out);
}

// Round 5
// 548.840 us; speedup vs baseline: 1.3890x; 1.0618x over previous
//
#include <hip/hip_runtime.h>

#define NN 20000
#define NE 320000
#define H  128
#define HH 64

typedef short bf16x8 __attribute__((ext_vector_type(8)));   // 8 bf16 = 4 VGPR
typedef float f32x4  __attribute__((ext_vector_type(4)));

__device__ __forceinline__ float lrelu(float v){ return fmaxf(v, 0.2f*v); }
__device__ __forceinline__ float as_f(unsigned u){ return __uint_as_float(u); }

// packed fp32->bf16 (RNE), 2 floats -> 1 u32 [lo16=cvt(a), hi16=cvt(b)]
__device__ __forceinline__ unsigned pk_bf16(float a, float b){
  unsigned r;
  asm("v_cvt_pk_bf16_f32 %0, %1, %2" : "=v"(r) : "v"(a), "v"(b));
  return r;
}

// ---------------- node feature init ----------------
__global__ __launch_bounds__(256) void k_node_init(
    const float* __restrict__ shapes, const int* __restrict__ gid,
    const float* __restrict__ emb, const float* __restrict__ dimW,
    const float* __restrict__ dimb, float* __restrict__ x)
{
  int idx = blockIdx.x*256 + threadIdx.x;
  if (idx >= NN*H) return;
  int n = idx >> 7, j = idx & 127;
  float v;
  if (j < HH) v = shapes[n]*dimW[j] + dimb[j];
  else        v = emb[gid[n]*HH + (j-HH)];
  x[idx] = v;
}

// ---------------- CSR build ----------------
__global__ __launch_bounds__(256) void k_count(const int* __restrict__ dst, int* __restrict__ deg){
  int e = blockIdx.x*256 + threadIdx.x;
  if (e < NE) atomicAdd(&deg[dst[e]], 1);
}

__global__ __launch_bounds__(1024) void k_scan(const int* __restrict__ deg, int* __restrict__ off){
  __shared__ int ps[1024];
  int t = threadIdx.x;
  const int CH = (NN + 1023)/1024;   // 20
  int base = t*CH;
  int s = 0;
  for (int i=0;i<CH;i++){ int g=base+i; if (g<NN) s += deg[g]; }
  ps[t] = s; __syncthreads();
  for (int d=1; d<1024; d<<=1){
    int v = (t>=d) ? ps[t-d] : 0;
    __syncthreads();
    ps[t] += v;
    __syncthreads();
  }
  int run = (t==0) ? 0 : ps[t-1];
  for (int i=0;i<CH;i++){ int g=base+i; if (g<NN){ off[g]=run; run += deg[g]; } }
  if (t==1023) off[NN] = run;
}

__global__ __launch_bounds__(256) void k_fill(const int* __restrict__ src, const int* __restrict__ dst,
    const int* __restrict__ off, int* __restrict__ cur, int* __restrict__ csr){
  int e = blockIdx.x*256 + threadIdx.x;
  if (e < NE){
    int d = dst[e];
    int p = atomicAdd(&cur[d], 1);
    csr[off[d]+p] = src[e];
  }
}

// ---------------- SAGE mean aggregation (1 wave / node) ----------------
__global__ __launch_bounds__(256) void k_aggr(const float* __restrict__ x,
    const int* __restrict__ off, const int* __restrict__ csr, float* __restrict__ agg)
{
  int wid = (blockIdx.x*256 + threadIdx.x) >> 6;
  int lane = threadIdx.x & 63;
  if (wid >= NN) return;
  int b = off[wid], e = off[wid+1];
  float a0=0.f, a1=0.f;
  for (int i=b;i<e;i++){
    int s = csr[i];
    a0 += x[s*H + lane];
    a1 += x[s*H + 64 + lane];
  }
  float inv = 1.0f / fmaxf((float)(e-b), 1.0f);
  agg[wid*H + lane]      = a0*inv;
  agg[wid*H + 64 + lane] = a1*inv;
}

// ---------------- fused node GEMM (fp32 VALU): Y = [relu]( A@W1 [+ B@W2] [+ bias] ) ----------------
template<bool TWO, bool RELU, bool BIAS>
__global__ __launch_bounds__(256) void k_gemm(
    const float* __restrict__ A, const float* __restrict__ W1,
    const float* __restrict__ B, const float* __restrict__ W2,
    const float* __restrict__ bias, float* __restrict__ Y, int M)
{
  __shared__ float T[64][132];
  int tid = threadIdx.x;
  int row0 = blockIdx.x*64;
  int eg = tid >> 4, cg = tid & 15;

  float acc[4][8];
  #pragma unroll
  for (int r=0;r<4;r++)
    #pragma unroll
    for (int c=0;c<8;c++) acc[r][c]=0.f;

  const int npass = TWO ? 2 : 1;
  for (int pass=0; pass<npass; pass++){
    const float* S = (pass==0)? A  : B;
    const float* W = (pass==0)? W1 : W2;
    if (pass==1) __syncthreads();
    #pragma unroll
    for (int i=0;i<8;i++){
      int idx = tid + i*256;
      int r = idx >> 5, c4 = idx & 31;
      int row = row0 + r;
      float4 v = make_float4(0.f,0.f,0.f,0.f);
      if (row < M) v = *(const float4*)&S[row*H + c4*4];
      *(float4*)&T[r][c4*4] = v;
    }
    __syncthreads();
    for (int kb=0; kb<32; kb++){
      float wv[4][8];
      #pragma unroll
      for (int t=0;t<4;t++){
        float4 wa = *(const float4*)&W[(kb*4+t)*H + cg*8];
        float4 wb = *(const float4*)&W[(kb*4+t)*H + cg*8 + 4];
        wv[t][0]=wa.x; wv[t][1]=wa.y; wv[t][2]=wa.z; wv[t][3]=wa.w;
        wv[t][4]=wb.x; wv[t][5]=wb.y; wv[t][6]=wb.z; wv[t][7]=wb.w;
      }
      #pragma unroll
      for (int r=0;r<4;r++){
        float4 a = *(const float4*)&T[eg + r*16][kb*4];
        float av[4] = {a.x, a.y, a.z, a.w};
        #pragma unroll
        for (int t=0;t<4;t++)
          #pragma unroll
          for (int c=0;c<8;c++)
            acc[r][c] = fmaf(av[t], wv[t][c], acc[r][c]);
      }
    }
  }

  float bv[8];
  if constexpr (BIAS){
    float4 ba = *(const float4*)&bias[cg*8];
    float4 bb = *(const float4*)&bias[cg*8+4];
    bv[0]=ba.x; bv[1]=ba.y; bv[2]=ba.z; bv[3]=ba.w;
    bv[4]=bb.x; bv[5]=bb.y; bv[6]=bb.z; bv[7]=bb.w;
  } else {
    #pragma unroll
    for (int c=0;c<8;c++) bv[c]=0.f;
  }
  #pragma unroll
  for (int r=0;r<4;r++){
    int row = row0 + eg + r*16;
    if (row < M){
      float o[8];
      #pragma unroll
      for (int c=0;c<8;c++){
        float v = acc[r][c] + bv[c];
        o[c] = RELU ? fmaxf(v, 0.f) : v;
      }
      *(float4*)&Y[row*H + cg*8]     = make_float4(o[0],o[1],o[2],o[3]);
      *(float4*)&Y[row*H + cg*8 + 4] = make_float4(o[4],o[5],o[6],o[7]);
    }
  }
}

// ---------------- GAT per-node scalars ----------------
__global__ __launch_bounds__(256) void k_scal(const float* __restrict__ h,
    const float* __restrict__ asrc, const float* __restrict__ adst,
    float* __restrict__ hs, float* __restrict__ hd)
{
  int wid = (blockIdx.x*256 + threadIdx.x) >> 6;
  int lane = threadIdx.x & 63;
  if (wid >= NN) return;
  float h0 = h[wid*H + lane], h1 = h[wid*H + 64 + lane];
  float s = h0*asrc[lane] + h1*asrc[64+lane];
  float d = h0*adst[lane] + h1*adst[64+lane];
  #pragma unroll
  for (int o=32;o>0;o>>=1){ s += __shfl_down(s,o); d += __shfl_down(d,o); }
  if (lane==0){ hs[wid]=s; hd[wid]=d; }
}

// ---------------- GAT aggregation ----------------
__global__ __launch_bounds__(256) void k_gat(
    const float* __restrict__ h, const float* __restrict__ hs, const float* __restrict__ hd,
    const int* __restrict__ off, const int* __restrict__ csr,
    const float* __restrict__ bias, float* __restrict__ y)
{
  int wid = (blockIdx.x*256 + threadIdx.x) >> 6;
  int lane = threadIdx.x & 63;
  if (wid >= NN) return;
  int b = off[wid], e = off[wid+1];
  float hdv = hd[wid];
  float eself = lrelu(hs[wid] + hdv);
  float m = eself;
  for (int i=b;i<e;i++) m = fmaxf(m, lrelu(hs[csr[i]] + hdv));
  float z = expf(eself - m);
  float a0 = z * h[wid*H + lane];
  float a1 = z * h[wid*H + 64 + lane];
  for (int i=b;i<e;i++){
    int s = csr[i];
    float p = expf(lrelu(hs[s] + hdv) - m);
    z += p;
    a0 = fmaf(p, h[s*H + lane], a0);
    a1 = fmaf(p, h[s*H + 64 + lane], a1);
  }
  float inv = 1.0f / z;
  y[wid*H + lane]      = fmaxf(a0*inv + bias[lane], 0.f);
  y[wid*H + 64 + lane] = fmaxf(a1*inv + bias[64+lane], 0.f);
}

// ================= MFMA edge MLP (bf16x2 split precision) =================
// Frag layout (16x16x32): lane l supplies A[m=l&15][k-slot g=l>>4, j=0..7],
// B[k-slot][n=l&15]; k = kc*32 + g*8 + j (same bijection both sides — safe).
// C (m89-verified): row=(l>>4)*4+r, col=l&15.
// One 32 KB LDS region time-shared: A1 -> W1.h0 -> W1.h1 -> A2 -> W2.h0 -> W2.h1.
// W pre-converted once by k_wconv into frag-linear bf16 hi/lo uint4s.

// pre-convert W1,W2 (fp32 row-major [128][128]) -> wcvt[(L*2+hf)*2048 + {hi:0,lo:1024} + bw*64+s]
__global__ __launch_bounds__(256) void k_wconv(const float* __restrict__ W1,
    const float* __restrict__ W2, uint4* __restrict__ outw)
{
  int t = blockIdx.x*256 + threadIdx.x;       // 0..4095
  int L = t >> 11, hf = (t >> 10) & 1, bw = (t >> 6) & 15, s = t & 63;
  const float* W = L ? W2 : W1;
  int row0 = (bw & 3)*32 + (s >> 4)*8;        // kc=bw&3, g=s>>4
  int col  = hf*64 + (bw >> 2)*16 + (s & 15);
  const float* p = W + row0*128 + col;
  float f[8];
  #pragma unroll
  for (int j=0;j<8;j++) f[j] = p[j*128];
  unsigned h0=pk_bf16(f[0],f[1]), h1=pk_bf16(f[2],f[3]),
           h2=pk_bf16(f[4],f[5]), h3=pk_bf16(f[6],f[7]);
  unsigned l0=pk_bf16(f[0]-as_f(h0<<16), f[1]-as_f(h0&0xffff0000u));
  unsigned l1=pk_bf16(f[2]-as_f(h1<<16), f[3]-as_f(h1&0xffff0000u));
  unsigned l2=pk_bf16(f[4]-as_f(h2<<16), f[5]-as_f(h2&0xffff0000u));
  unsigned l3=pk_bf16(f[6]-as_f(h3<<16), f[7]-as_f(h3&0xffff0000u));
  int base = (L*2 + hf)*2048;
  outw[base + bw*64 + s]        = make_uint4(h0,h1,h2,h3);
  outw[base + 1024 + bw*64 + s] = make_uint4(l0,l1,l2,l3);
}

// copy one pre-converted 32KB half-layer into LDS (coalesced)
__device__ __forceinline__ void copyW(const uint4* __restrict__ srcw, uint4* R, int tid){
  #pragma unroll
  for (int i=0;i<8;i++) R[tid + i*256] = srcw[tid + i*256];
}

// one column-half of MFMAs: nt = HF*4+ntl, 3 MFMAs per (nt,kc) for bf16x2
template<int HF>
__device__ __forceinline__ void mfma_half(f32x4* acc, const bf16x8* ah, const bf16x8* al,
                                          const uint4* R, int l)
{
  #pragma unroll
  for (int ntl=0; ntl<4; ntl++){
    f32x4 a = acc[HF*4 + ntl];
    #pragma unroll
    for (int kc=0; kc<4; kc++){
      bf16x8 bh = __builtin_bit_cast(bf16x8, R[(ntl*4+kc)*64 + l]);
      bf16x8 bl = __builtin_bit_cast(bf16x8, R[1024 + (ntl*4+kc)*64 + l]);
      a = __builtin_amdgcn_mfma_f32_16x16x32_bf16(ah[kc], bh, a, 0, 0, 0);
      a = __builtin_amdgcn_mfma_f32_16x16x32_bf16(ah[kc], bl, a, 0, 0, 0);
      a = __builtin_amdgcn_mfma_f32_16x16x32_bf16(al[kc], bh, a, 0, 0, 0);
    }
    acc[HF*4 + ntl] = a;
  }
}

__global__ __launch_bounds__(256) void k_edge_mfma(
    const float* __restrict__ x, const int* __restrict__ src, const int* __restrict__ dst,
    const uint4* __restrict__ wcvt,
    const float* __restrict__ b1, const float* __restrict__ b2,
    const float* __restrict__ outW, const float* __restrict__ outb,
    float* __restrict__ out)
{
  __shared__ uint4 R[2048];                   // 32 KB, time-shared
  const int tid = threadIdx.x;
  const int l = tid & 63, w = tid >> 6;
  const int e0 = blockIdx.x * 64;

  // ---- gather: E = x[src]+x[dst], split bf16 hi/lo, frag-linear into R ----
  // wave w supplies k-chunk kc=w for all 64 edges; lane l = edge row.
  {
    int e = e0 + l;
    int sn = src[e], dn = dst[e];
    const float4* ps = (const float4*)(x + (size_t)sn*H + w*32);
    const float4* pd = (const float4*)(x + (size_t)dn*H + w*32);
    float ev[32];
    #pragma unroll
    for (int q=0;q<8;q++){
      float4 a = ps[q], b = pd[q];
      ev[q*4+0]=a.x+b.x; ev[q*4+1]=a.y+b.y; ev[q*4+2]=a.z+b.z; ev[q*4+3]=a.w+b.w;
    }
    int blk = ((l>>4)*4 + w)*64;              // rt*4 + kc
    #pragma unroll
    for (int g=0; g<4; g++){
      unsigned hp[4], lp[4];
      #pragma unroll
      for (int q=0;q<4;q++){
        float f0 = ev[g*8+q*2], f1 = ev[g*8+q*2+1];
        unsigned h = pk_bf16(f0, f1);
        hp[q] = h;
        lp[q] = pk_bf16(f0 - as_f(h<<16), f1 - as_f(h & 0xffff0000u));
      }
      int ai = blk + (l&15) + 16*g;
      R[ai]        = make_uint4(hp[0],hp[1],hp[2],hp[3]);
      R[1024 + ai] = make_uint4(lp[0],lp[1],lp[2],lp[3]);
    }
  }
  __syncthreads();                                       // B1: A1 staged

  bf16x8 ah[4], al[4];
  #pragma unroll
  for (int kc=0; kc<4; kc++){
    ah[kc] = __builtin_bit_cast(bf16x8, R[(w*4+kc)*64 + l]);
    al[kc] = __builtin_bit_cast(bf16x8, R[1024 + (w*4+kc)*64 + l]);
  }
  __syncthreads();                                       // B2: A1 reads done
  copyW(wcvt + 0*2048, R, tid);                          // W1.h0
  __syncthreads();                                       // B3

  f32x4 acc[8];
  #pragma unroll
  for (int i=0;i<8;i++) acc[i] = 0.f;
  mfma_half<0>(acc, ah, al, R, l);
  __syncthreads();                                       // B4
  copyW(wcvt + 1*2048, R, tid);                          // W1.h1
  __syncthreads();                                       // B5
  mfma_half<1>(acc, ah, al, R, l);
  __syncthreads();                                       // B6: W reads done

  // ---- epilogue 1: bias+relu, split, scatter A2 frags (wave-private region) ----
  {
    float b1v[8];
    #pragma unroll
    for (int nt=0;nt<8;nt++) b1v[nt] = b1[nt*16 + (l&15)];
    #pragma unroll
    for (int nt=0;nt<8;nt++){
      int b2blk = w*4 + (nt>>1);                         // rt2*4 + kc2
      int gp = (2*nt + ((l&15)>>3)) & 3;                 // k-slot group of col
      #pragma unroll
      for (int r=0;r<4;r++){
        float v = fmaxf(acc[nt][r] + b1v[nt], 0.f);
        unsigned h = pk_bf16(v, v);
        unsigned lo = pk_bf16(v - as_f(h<<16), 0.f);
        int sp = (4*(l>>4) + r) + 16*gp;
        int off = (b2blk*64 + sp)*16 + (l&7)*2;
        *(short*)((char*)R + off)         = (short)(h  & 0xffff);
        *(short*)((char*)R + 16384 + off) = (short)(lo & 0xffff);
      }
    }
  }
  // same-wave LDS write->read ordering: no barrier needed (wave-private region)
  #pragma unroll
  for (int kc=0; kc<4; kc++){
    ah[kc] = __builtin_bit_cast(bf16x8, R[(w*4+kc)*64 + l]);
    al[kc] = __builtin_bit_cast(bf16x8, R[1024 + (w*4+kc)*64 + l]);
  }
  __syncthreads();                                       // B7: A2 reads done
  copyW(wcvt + 2*2048, R, tid);                          // W2.h0
  __syncthreads();                                       // B8

  f32x4 acc2[8];
  #pragma unroll
  for (int i=0;i<8;i++) acc2[i] = 0.f;
  mfma_half<0>(acc2, ah, al, R, l);
  __syncthreads();                                       // B9
  copyW(wcvt + 3*2048, R, tid);                          // W2.h1
  __syncthreads();                                       // B10
  mfma_half<1>(acc2, ah, al, R, l);

  // ---- epilogue 2: bias+relu, dot outW, reduce over 16 col-lanes ----
  {
    float b2v[8], owv[8];
    #pragma unroll
    for (int nt=0;nt<8;nt++){
      b2v[nt] = b2[nt*16 + (l&15)];
      owv[nt] = outW[nt*16 + (l&15)];
    }
    float ob = outb[0];
    #pragma unroll
    for (int r=0;r<4;r++){
      float p = 0.f;
      #pragma unroll
      for (int nt=0;nt<8;nt++)
        p = fmaf(fmaxf(acc2[nt][r] + b2v[nt], 0.f), owv[nt], p);
      #pragma unroll
      for (int m=1;m<16;m<<=1) p += __shfl_xor(p, m, 16);
      if ((l&15)==0) out[e0 + w*16 + (l>>4)*4 + r] = p + ob;
    }
  }
}

// ---------------- launch ----------------
extern "C" void kernel_launch(void* const* d_in, const int* in_sizes, int n_in,
                              void* d_out, int out_size, void* d_ws, size_t ws_size,
                              hipStream_t stream)
{
  const float* shapes   = (const float*)d_in[0];
  const int*   gate_ids = (const int*)  d_in[1];
  const int*   ei       = (const int*)  d_in[2];
  const float* emb      = (const float*)d_in[3];
  const float* dimW     = (const float*)d_in[4];
  const float* dimb     = (const float*)d_in[5];
  const float* sage_Wl  = (const float*)d_in[6];
  const float* sage_bl  = (const float*)d_in[7];
  const float* sage_Wr  = (const float*)d_in[8];
  const float* gat_W    = (const float*)d_in[9];
  const float* gat_asrc = (const float*)d_in[10];
  const float* gat_adst = (const float*)d_in[11];
  const float* gat_b    = (const float*)d_in[12];
  const float* edgeW    = (const float*)d_in[13];
  const float* edgeb    = (const float*)d_in[14];
  const float* outW     = (const float*)d_in[15];
  const float* outb     = (const float*)d_in[16];
  const int* src = ei;
  const int* dst = ei + NE;

  char* w = (char*)d_ws;
  auto alloc = [&](size_t bytes)->void* {
    void* p = (void*)w; w += (bytes + 255) & ~(size_t)255; return p;
  };
  float* xa   = (float*)alloc((size_t)NN*H*4);
  float* xb   = (float*)alloc((size_t)NN*H*4);
  float* agg  = (float*)alloc((size_t)NN*H*4);
  float* hs   = (float*)alloc((size_t)NN*4);
  float* hd   = (float*)alloc((size_t)NN*4);
  int*   deg  = (int*)alloc((size_t)NN*4);
  int*   off  = (int*)alloc((size_t)(NN+1)*4);
  int*   cur  = (int*)alloc((size_t)NN*4);
  int*   csr  = (int*)alloc((size_t)NE*4);
  uint4* wcvt = (uint4*)alloc((size_t)8192*16);   // 128 KB pre-converted edge W

  hipMemsetAsync(deg, 0, (size_t)NN*4, stream);
  hipMemsetAsync(cur, 0, (size_t)NN*4, stream);

  k_node_init<<<(NN*H+255)/256, 256, 0, stream>>>(shapes, gate_ids, emb, dimW, dimb, xa);
  k_count<<<(NE+255)/256, 256, 0, stream>>>(dst, deg);
  k_scan<<<1, 1024, 0, stream>>>(deg, off);
  k_fill<<<(NE+255)/256, 256, 0, stream>>>(src, dst, off, cur, csr);
  k_wconv<<<16, 256, 0, stream>>>(edgeW, edgeW + H*H, wcvt);

  float* xin = xa; float* xout = xb;
  const int gemm_blocks = (NN+63)/64;
  for (int i=0;i<3;i++){
    k_aggr<<<NN/4, 256, 0, stream>>>(xin, off, csr, agg);
    k_gemm<true,true,true><<<gemm_blocks, 256, 0, stream>>>(
        agg, sage_Wl + (size_t)i*H*H, xin, sage_Wr + (size_t)i*H*H,
        sage_bl + (size_t)i*H, xout, NN);
    float* t = xin; xin = xout; xout = t;
  }

  k_gemm<false,false,false><<<gemm_blocks, 256, 0, stream>>>(
      xin, gat_W, nullptr, nullptr, nullptr, agg, NN);
  k_scal<<<NN/4, 256, 0, stream>>>(agg, gat_asrc, gat_adst, hs, hd);
  k_gat<<<NN/4, 256, 0, stream>>>(agg, hs, hd, off, csr, gat_b, xout);
  { float* t = xin; xin = xout; xout = t; }

  k_edge_mfma<<<NE/64, 256, 0, stream>>>(xin, src, dst, wcvt,
      edgeb, edgeb + H, outW, outb, (float*)d_out);
}

// Round 6
// 472.785 us; speedup vs baseline: 1.6124x; 1.1609x over previous
//
#include <hip/hip_runtime.h>

#define NN 20000
#define NE 320000
#define H  128
#define HH 64

typedef short bf16x8 __attribute__((ext_vector_type(8)));   // 8 bf16 = 4 VGPR
typedef float f32x4  __attribute__((ext_vector_type(4)));

__device__ __forceinline__ float lrelu(float v){ return fmaxf(v, 0.2f*v); }
__device__ __forceinline__ float as_f(unsigned u){ return __uint_as_float(u); }

// packed fp32->bf16 (RNE), 2 floats -> 1 u32 [lo16=cvt(a), hi16=cvt(b)]
__device__ __forceinline__ unsigned pk_bf16(float a, float b){
  unsigned r;
  asm("v_cvt_pk_bf16_f32 %0, %1, %2" : "=v"(r) : "v"(a), "v"(b));
  return r;
}

// ---------------- node feature init ----------------
__global__ __launch_bounds__(256) void k_node_init(
    const float* __restrict__ shapes, const int* __restrict__ gid,
    const float* __restrict__ emb, const float* __restrict__ dimW,
    const float* __restrict__ dimb, float* __restrict__ x)
{
  int idx = blockIdx.x*256 + threadIdx.x;
  if (idx >= NN*H) return;
  int n = idx >> 7, j = idx & 127;
  float v;
  if (j < HH) v = shapes[n]*dimW[j] + dimb[j];
  else        v = emb[gid[n]*HH + (j-HH)];
  x[idx] = v;
}

// ---------------- CSR build ----------------
__global__ __launch_bounds__(256) void k_count(const int* __restrict__ dst, int* __restrict__ deg){
  int e = blockIdx.x*256 + threadIdx.x;
  if (e < NE) atomicAdd(&deg[dst[e]], 1);
}

__global__ __launch_bounds__(1024) void k_scan(const int* __restrict__ deg, int* __restrict__ off){
  __shared__ int ps[1024];
  int t = threadIdx.x;
  const int CH = (NN + 1023)/1024;   // 20
  int base = t*CH;
  int s = 0;
  for (int i=0;i<CH;i++){ int g=base+i; if (g<NN) s += deg[g]; }
  ps[t] = s; __syncthreads();
  for (int d=1; d<1024; d<<=1){
    int v = (t>=d) ? ps[t-d] : 0;
    __syncthreads();
    ps[t] += v;
    __syncthreads();
  }
  int run = (t==0) ? 0 : ps[t-1];
  for (int i=0;i<CH;i++){ int g=base+i; if (g<NN){ off[g]=run; run += deg[g]; } }
  if (t==1023) off[NN] = run;
}

__global__ __launch_bounds__(256) void k_fill(const int* __restrict__ src, const int* __restrict__ dst,
    const int* __restrict__ off, int* __restrict__ cur, int* __restrict__ csr){
  int e = blockIdx.x*256 + threadIdx.x;
  if (e < NE){
    int d = dst[e];
    int p = atomicAdd(&cur[d], 1);
    csr[off[d]+p] = src[e];
  }
}

// ---------------- SAGE mean aggregation (1 wave / node, float2 lanes) ----------------
__global__ __launch_bounds__(256) void k_aggr(const float* __restrict__ x,
    const int* __restrict__ off, const int* __restrict__ csr, float* __restrict__ agg)
{
  int wid = (blockIdx.x*256 + threadIdx.x) >> 6;
  int lane = threadIdx.x & 63;
  if (wid >= NN) return;
  int b = off[wid], e = off[wid+1];
  float ax=0.f, ay=0.f;
  for (int i=b;i<e;i++){
    int s = csr[i];
    float2 v = *(const float2*)&x[(size_t)s*H + lane*2];
    ax += v.x; ay += v.y;
  }
  float inv = 1.0f / fmaxf((float)(e-b), 1.0f);
  *(float2*)&agg[(size_t)wid*H + lane*2] = make_float2(ax*inv, ay*inv);
}

// ---------------- GAT aggregation (float2 lanes) ----------------
__global__ __launch_bounds__(256) void k_gat(
    const float* __restrict__ h, const float* __restrict__ hs, const float* __restrict__ hd,
    const int* __restrict__ off, const int* __restrict__ csr,
    const float* __restrict__ bias, float* __restrict__ y)
{
  int wid = (blockIdx.x*256 + threadIdx.x) >> 6;
  int lane = threadIdx.x & 63;
  if (wid >= NN) return;
  int b = off[wid], e = off[wid+1];
  float hdv = hd[wid];
  float eself = lrelu(hs[wid] + hdv);
  float m = eself;
  for (int i=b;i<e;i++) m = fmaxf(m, lrelu(hs[csr[i]] + hdv));
  float z = expf(eself - m);
  float2 hv = *(const float2*)&h[(size_t)wid*H + lane*2];
  float ax = z*hv.x, ay = z*hv.y;
  for (int i=b;i<e;i++){
    int s = csr[i];
    float p = expf(lrelu(hs[s] + hdv) - m);
    z += p;
    float2 u = *(const float2*)&h[(size_t)s*H + lane*2];
    ax = fmaf(p, u.x, ax);
    ay = fmaf(p, u.y, ay);
  }
  float inv = 1.0f / z;
  float2 bv = *(const float2*)&bias[lane*2];
  *(float2*)&y[(size_t)wid*H + lane*2] =
      make_float2(fmaxf(ax*inv + bv.x, 0.f), fmaxf(ay*inv + bv.y, 0.f));
}

// ================= shared MFMA machinery (bf16x2 split precision) =================
// Frag (16x16x32): lane l: A[m=l&15][k = kc*32 + (l>>4)*8 + j]; same k bijection
// for B. C: row=(l>>4)*4+r, col=l&15 (m89-verified; passed R4/R5 correctness).
// wcvt layout: matrix m at m*4096 uint4; half hf at +hf*2048; {hi:0, lo:+1024}; [bw*64+s].

// pre-convert 9 weight matrices: 0,1=edgeW; 2..4=sage_Wl; 5..7=sage_Wr; 8=gat_W
__global__ __launch_bounds__(256) void k_wconv_multi(
    const float* __restrict__ edgeW, const float* __restrict__ Wl,
    const float* __restrict__ Wr, const float* __restrict__ gatW,
    uint4* __restrict__ outw)
{
  int t = blockIdx.x*256 + threadIdx.x;       // 0..18431 (9 * 2048)
  int m = t >> 11;
  int r = t & 2047;
  int hf = r >> 10, bw = (r >> 6) & 15, s = r & 63;
  const float* W;
  if      (m < 2) W = edgeW + (size_t)m*16384;
  else if (m < 5) W = Wl    + (size_t)(m-2)*16384;
  else if (m < 8) W = Wr    + (size_t)(m-5)*16384;
  else            W = gatW;
  int row0 = (bw & 3)*32 + (s >> 4)*8;        // kc=bw&3, g=s>>4
  int col  = hf*64 + (bw >> 2)*16 + (s & 15);
  const float* p = W + row0*128 + col;
  float f[8];
  #pragma unroll
  for (int j=0;j<8;j++) f[j] = p[j*128];
  unsigned h0=pk_bf16(f[0],f[1]), h1=pk_bf16(f[2],f[3]),
           h2=pk_bf16(f[4],f[5]), h3=pk_bf16(f[6],f[7]);
  unsigned l0=pk_bf16(f[0]-as_f(h0<<16), f[1]-as_f(h0&0xffff0000u));
  unsigned l1=pk_bf16(f[2]-as_f(h1<<16), f[3]-as_f(h1&0xffff0000u));
  unsigned l2=pk_bf16(f[4]-as_f(h2<<16), f[5]-as_f(h2&0xffff0000u));
  unsigned l3=pk_bf16(f[6]-as_f(h3<<16), f[7]-as_f(h3&0xffff0000u));
  int base = m*4096 + hf*2048;
  outw[base + bw*64 + s]        = make_uint4(h0,h1,h2,h3);
  outw[base + 1024 + bw*64 + s] = make_uint4(l0,l1,l2,l3);
}

// copy one pre-converted 32KB half-layer into LDS (coalesced)
__device__ __forceinline__ void copyW(const uint4* __restrict__ srcw, uint4* R, int tid){
  #pragma unroll
  for (int i=0;i<8;i++) R[tid + i*256] = srcw[tid + i*256];
}

// one column-half of MFMAs: nt = HF*4+ntl, 3 MFMAs per (nt,kc) for bf16x2
template<int HF>
__device__ __forceinline__ void mfma_half(f32x4* acc, const bf16x8* ah, const bf16x8* al,
                                          const uint4* R, int l)
{
  #pragma unroll
  for (int ntl=0; ntl<4; ntl++){
    f32x4 a = acc[HF*4 + ntl];
    #pragma unroll
    for (int kc=0; kc<4; kc++){
      bf16x8 bh = __builtin_bit_cast(bf16x8, R[(ntl*4+kc)*64 + l]);
      bf16x8 bl = __builtin_bit_cast(bf16x8, R[1024 + (ntl*4+kc)*64 + l]);
      a = __builtin_amdgcn_mfma_f32_16x16x32_bf16(ah[kc], bh, a, 0, 0, 0);
      a = __builtin_amdgcn_mfma_f32_16x16x32_bf16(ah[kc], bl, a, 0, 0, 0);
      a = __builtin_amdgcn_mfma_f32_16x16x32_bf16(al[kc], bh, a, 0, 0, 0);
    }
    acc[HF*4 + ntl] = a;
  }
}

// stage 4 A-frags (one row, k=0..127) from global fp32 into bf16 hi/lo regs
__device__ __forceinline__ void stageA(const float* __restrict__ Ap, bool valid, int g8,
                                       bf16x8* ah, bf16x8* al)
{
  #pragma unroll
  for (int kc=0;kc<4;kc++){
    float f[8];
    if (valid){
      float4 u = *(const float4*)&Ap[kc*32 + g8];
      float4 v = *(const float4*)&Ap[kc*32 + g8 + 4];
      f[0]=u.x; f[1]=u.y; f[2]=u.z; f[3]=u.w; f[4]=v.x; f[5]=v.y; f[6]=v.z; f[7]=v.w;
    } else {
      #pragma unroll
      for (int j=0;j<8;j++) f[j]=0.f;
    }
    unsigned hp[4], lp[4];
    #pragma unroll
    for (int q=0;q<4;q++){
      unsigned hh = pk_bf16(f[2*q], f[2*q+1]);
      hp[q] = hh;
      lp[q] = pk_bf16(f[2*q]-as_f(hh<<16), f[2*q+1]-as_f(hh & 0xffff0000u));
    }
    ah[kc] = __builtin_bit_cast(bf16x8, make_uint4(hp[0],hp[1],hp[2],hp[3]));
    al[kc] = __builtin_bit_cast(bf16x8, make_uint4(lp[0],lp[1],lp[2],lp[3]));
  }
}

// ---------------- node GEMM via MFMA: Y = relu(A1@W1 + A2@W2 + b)  |  GAT: h=A1@W, +hs/hd ----------------
template<bool TWO, bool GATEP>
__global__ __launch_bounds__(256) void k_ngemm(
    const float* __restrict__ A1, const float* __restrict__ A2,
    const uint4* __restrict__ wc1, const uint4* __restrict__ wc2,
    const float* __restrict__ bias, float* __restrict__ Y,
    const float* __restrict__ asrc, const float* __restrict__ adst,
    float* __restrict__ hs, float* __restrict__ hd, int M)
{
  __shared__ uint4 R[2048];                   // 32 KB, time-shared for W halves
  const int tid = threadIdx.x;
  const int l = tid & 63, w = tid >> 6;
  const int row0 = blockIdx.x*64;
  const int arow = row0 + w*16 + (l&15);
  const bool avld = arow < M;
  const int g8 = (l>>4)*8;

  bf16x8 ah[4], al[4];
  stageA(A1 + (size_t)arow*H, avld, g8, ah, al);

  f32x4 acc[8];
  #pragma unroll
  for (int i=0;i<8;i++) acc[i] = 0.f;

  copyW(wc1, R, tid); __syncthreads();
  mfma_half<0>(acc, ah, al, R, l);
  __syncthreads(); copyW(wc1 + 2048, R, tid); __syncthreads();
  mfma_half<1>(acc, ah, al, R, l);

  if constexpr (TWO){
    stageA(A2 + (size_t)arow*H, avld, g8, ah, al);
    __syncthreads(); copyW(wc2, R, tid); __syncthreads();
    mfma_half<0>(acc, ah, al, R, l);
    __syncthreads(); copyW(wc2 + 2048, R, tid); __syncthreads();
    mfma_half<1>(acc, ah, al, R, l);
  }

  if constexpr (!GATEP){
    float bv[8];
    #pragma unroll
    for (int nt=0;nt<8;nt++) bv[nt] = bias[nt*16 + (l&15)];
    #pragma unroll
    for (int r=0;r<4;r++){
      int srow = row0 + w*16 + (l>>4)*4 + r;
      if (srow < M){
        #pragma unroll
        for (int nt=0;nt<8;nt++)
          Y[(size_t)srow*H + nt*16 + (l&15)] = fmaxf(acc[nt][r] + bv[nt], 0.f);
      }
    }
  } else {
    float avv[8], dvv[8];
    #pragma unroll
    for (int nt=0;nt<8;nt++){
      avv[nt] = asrc[nt*16 + (l&15)];
      dvv[nt] = adst[nt*16 + (l&15)];
    }
    #pragma unroll
    for (int r=0;r<4;r++){
      int srow = row0 + w*16 + (l>>4)*4 + r;
      float sp = 0.f, dp = 0.f;
      #pragma unroll
      for (int nt=0;nt<8;nt++){
        float hv = acc[nt][r];
        sp = fmaf(hv, avv[nt], sp);
        dp = fmaf(hv, dvv[nt], dp);
        if (srow < M) Y[(size_t)srow*H + nt*16 + (l&15)] = hv;
      }
      #pragma unroll
      for (int mm=1; mm<16; mm<<=1){
        sp += __shfl_xor(sp, mm, 16);
        dp += __shfl_xor(dp, mm, 16);
      }
      if ((l&15)==0 && srow < M){ hs[srow] = sp; hd[srow] = dp; }
    }
  }
}

// ================= MFMA edge MLP (unchanged from R5, passes) =================
__global__ __launch_bounds__(256) void k_edge_mfma(
    const float* __restrict__ x, const int* __restrict__ src, const int* __restrict__ dst,
    const uint4* __restrict__ wcvt,
    const float* __restrict__ b1, const float* __restrict__ b2,
    const float* __restrict__ outW, const float* __restrict__ outb,
    float* __restrict__ out)
{
  __shared__ uint4 R[2048];                   // 32 KB, time-shared
  const int tid = threadIdx.x;
  const int l = tid & 63, w = tid >> 6;
  const int e0 = blockIdx.x * 64;

  {
    int e = e0 + l;
    int sn = src[e], dn = dst[e];
    const float4* ps = (const float4*)(x + (size_t)sn*H + w*32);
    const float4* pd = (const float4*)(x + (size_t)dn*H + w*32);
    float ev[32];
    #pragma unroll
    for (int q=0;q<8;q++){
      float4 a = ps[q], b = pd[q];
      ev[q*4+0]=a.x+b.x; ev[q*4+1]=a.y+b.y; ev[q*4+2]=a.z+b.z; ev[q*4+3]=a.w+b.w;
    }
    int blk = ((l>>4)*4 + w)*64;              // rt*4 + kc
    #pragma unroll
    for (int g=0; g<4; g++){
      unsigned hp[4], lp[4];
      #pragma unroll
      for (int q=0;q<4;q++){
        float f0 = ev[g*8+q*2], f1 = ev[g*8+q*2+1];
        unsigned h = pk_bf16(f0, f1);
        hp[q] = h;
        lp[q] = pk_bf16(f0 - as_f(h<<16), f1 - as_f(h & 0xffff0000u));
      }
      int ai = blk + (l&15) + 16*g;
      R[ai]        = make_uint4(hp[0],hp[1],hp[2],hp[3]);
      R[1024 + ai] = make_uint4(lp[0],lp[1],lp[2],lp[3]);
    }
  }
  __syncthreads();                                       // B1: A1 staged

  bf16x8 ah[4], al[4];
  #pragma unroll
  for (int kc=0; kc<4; kc++){
    ah[kc] = __builtin_bit_cast(bf16x8, R[(w*4+kc)*64 + l]);
    al[kc] = __builtin_bit_cast(bf16x8, R[1024 + (w*4+kc)*64 + l]);
  }
  __syncthreads();                                       // B2: A1 reads done
  copyW(wcvt + 0*2048, R, tid);                          // W1.h0
  __syncthreads();                                       // B3

  f32x4 acc[8];
  #pragma unroll
  for (int i=0;i<8;i++) acc[i] = 0.f;
  mfma_half<0>(acc, ah, al, R, l);
  __syncthreads();                                       // B4
  copyW(wcvt + 1*2048, R, tid);                          // W1.h1
  __syncthreads();                                       // B5
  mfma_half<1>(acc, ah, al, R, l);
  __syncthreads();                                       // B6: W reads done

  {
    float b1v[8];
    #pragma unroll
    for (int nt=0;nt<8;nt++) b1v[nt] = b1[nt*16 + (l&15)];
    #pragma unroll
    for (int nt=0;nt<8;nt++){
      int b2blk = w*4 + (nt>>1);                         // rt2*4 + kc2
      int gp = (2*nt + ((l&15)>>3)) & 3;                 // k-slot group of col
      #pragma unroll
      for (int r=0;r<4;r++){
        float v = fmaxf(acc[nt][r] + b1v[nt], 0.f);
        unsigned h = pk_bf16(v, v);
        unsigned lo = pk_bf16(v - as_f(h<<16), 0.f);
        int sp = (4*(l>>4) + r) + 16*gp;
        int off = (b2blk*64 + sp)*16 + (l&7)*2;
        *(short*)((char*)R + off)         = (short)(h  & 0xffff);
        *(short*)((char*)R + 16384 + off) = (short)(lo & 0xffff);
      }
    }
  }
  #pragma unroll
  for (int kc=0; kc<4; kc++){
    ah[kc] = __builtin_bit_cast(bf16x8, R[(w*4+kc)*64 + l]);
    al[kc] = __builtin_bit_cast(bf16x8, R[1024 + (w*4+kc)*64 + l]);
  }
  __syncthreads();                                       // B7: A2 reads done
  copyW(wcvt + 2*2048, R, tid);                          // W2.h0
  __syncthreads();                                       // B8

  f32x4 acc2[8];
  #pragma unroll
  for (int i=0;i<8;i++) acc2[i] = 0.f;
  mfma_half<0>(acc2, ah, al, R, l);
  __syncthreads();                                       // B9
  copyW(wcvt + 3*2048, R, tid);                          // W2.h1
  __syncthreads();                                       // B10
  mfma_half<1>(acc2, ah, al, R, l);

  {
    float b2v[8], owv[8];
    #pragma unroll
    for (int nt=0;nt<8;nt++){
      b2v[nt] = b2[nt*16 + (l&15)];
      owv[nt] = outW[nt*16 + (l&15)];
    }
    float ob = outb[0];
    #pragma unroll
    for (int r=0;r<4;r++){
      float p = 0.f;
      #pragma unroll
      for (int nt=0;nt<8;nt++)
        p = fmaf(fmaxf(acc2[nt][r] + b2v[nt], 0.f), owv[nt], p);
      #pragma unroll
      for (int m=1;m<16;m<<=1) p += __shfl_xor(p, m, 16);
      if ((l&15)==0) out[e0 + w*16 + (l>>4)*4 + r] = p + ob;
    }
  }
}

// ---------------- launch ----------------
extern "C" void kernel_launch(void* const* d_in, const int* in_sizes, int n_in,
                              void* d_out, int out_size, void* d_ws, size_t ws_size,
                              hipStream_t stream)
{
  const float* shapes   = (const float*)d_in[0];
  const int*   gate_ids = (const int*)  d_in[1];
  const int*   ei       = (const int*)  d_in[2];
  const float* emb      = (const float*)d_in[3];
  const float* dimW     = (const float*)d_in[4];
  const float* dimb     = (const float*)d_in[5];
  const float* sage_Wl  = (const float*)d_in[6];
  const float* sage_bl  = (const float*)d_in[7];
  const float* sage_Wr  = (const float*)d_in[8];
  const float* gat_W    = (const float*)d_in[9];
  const float* gat_asrc = (const float*)d_in[10];
  const float* gat_adst = (const float*)d_in[11];
  const float* gat_b    = (const float*)d_in[12];
  const float* edgeW    = (const float*)d_in[13];
  const float* edgeb    = (const float*)d_in[14];
  const float* outW     = (const float*)d_in[15];
  const float* outb     = (const float*)d_in[16];
  const int* src = ei;
  const int* dst = ei + NE;

  char* w = (char*)d_ws;
  auto alloc = [&](size_t bytes)->void* {
    void* p = (void*)w; w += (bytes + 255) & ~(size_t)255; return p;
  };
  float* xa   = (float*)alloc((size_t)NN*H*4);
  float* xb   = (float*)alloc((size_t)NN*H*4);
  float* agg  = (float*)alloc((size_t)NN*H*4);
  float* hs   = (float*)alloc((size_t)NN*4);
  float* hd   = (float*)alloc((size_t)NN*4);
  int*   deg  = (int*)alloc((size_t)NN*4);
  int*   off  = (int*)alloc((size_t)(NN+1)*4);
  int*   cur  = (int*)alloc((size_t)NN*4);
  int*   csr  = (int*)alloc((size_t)NE*4);
  uint4* wcvt = (uint4*)alloc((size_t)9*4096*16);   // 576 KB pre-converted weights

  hipMemsetAsync(deg, 0, (size_t)NN*4, stream);
  hipMemsetAsync(cur, 0, (size_t)NN*4, stream);

  k_node_init<<<(NN*H+255)/256, 256, 0, stream>>>(shapes, gate_ids, emb, dimW, dimb, xa);
  k_count<<<(NE+255)/256, 256, 0, stream>>>(dst, deg);
  k_scan<<<1, 1024, 0, stream>>>(deg, off);
  k_fill<<<(NE+255)/256, 256, 0, stream>>>(src, dst, off, cur, csr);
  k_wconv_multi<<<72, 256, 0, stream>>>(edgeW, sage_Wl, sage_Wr, gat_W, wcvt);

  float* xin = xa; float* xout = xb;
  const int gemm_blocks = (NN+63)/64;   // 313
  for (int i=0;i<3;i++){
    k_aggr<<<NN/4, 256, 0, stream>>>(xin, off, csr, agg);
    k_ngemm<true,false><<<gemm_blocks, 256, 0, stream>>>(
        agg, xin, wcvt + (size_t)(2+i)*4096, wcvt + (size_t)(5+i)*4096,
        sage_bl + (size_t)i*H, xout, nullptr, nullptr, nullptr, nullptr, NN);
    float* t = xin; xin = xout; xout = t;
  }

  // GAT: h = x@W (into agg) + per-node hs/hd scalars fused in epilogue
  k_ngemm<false,true><<<gemm_blocks, 256, 0, stream>>>(
      xin, nullptr, wcvt + (size_t)8*4096, nullptr,
      nullptr, agg, gat_asrc, gat_adst, hs, hd, NN);
  k_gat<<<NN/4, 256, 0, stream>>>(agg, hs, hd, off, csr, gat_b, xout);
  { float* t = xin; xin = xout; xout = t; }

  k_edge_mfma<<<NE/64, 256, 0, stream>>>(xin, src, dst, wcvt,
      edgeb, edgeb + H, outW, outb, (float*)d_out);
}

// Round 9
// 400.892 us; speedup vs baseline: 1.9016x; 1.1793x over previous
//
#include <hip/hip_runtime.h>

#define NN 20000
#define NE 320000
#define H  128
#define HH 64

typedef short bf16x8 __attribute__((ext_vector_type(8)));   // 8 bf16 = 4 VGPR
typedef float f32x4  __attribute__((ext_vector_type(4)));

__device__ __forceinline__ float lrelu(float v){ return fmaxf(v, 0.2f*v); }
__device__ __forceinline__ float as_f(unsigned u){ return __uint_as_float(u); }

// packed fp32->bf16 (RNE), 2 floats -> 1 u32 [lo16=cvt(a), hi16=cvt(b)]
__device__ __forceinline__ unsigned pk_bf16(float a, float b){
  unsigned r;
  asm("v_cvt_pk_bf16_f32 %0, %1, %2" : "=v"(r) : "v"(a), "v"(b));
  return r;
}

// ---------------- node feature init ----------------
__global__ __launch_bounds__(256) void k_node_init(
    const float* __restrict__ shapes, const int* __restrict__ gid,
    const float* __restrict__ emb, const float* __restrict__ dimW,
    const float* __restrict__ dimb, float* __restrict__ x)
{
  int idx = blockIdx.x*256 + threadIdx.x;
  if (idx >= NN*H) return;
  int n = idx >> 7, j = idx & 127;
  float v;
  if (j < HH) v = shapes[n]*dimW[j] + dimb[j];
  else        v = emb[gid[n]*HH + (j-HH)];
  x[idx] = v;
}

// ---------------- CSR build ----------------
__global__ __launch_bounds__(256) void k_count(const int* __restrict__ dst, int* __restrict__ deg){
  int e = blockIdx.x*256 + threadIdx.x;
  if (e < NE) atomicAdd(&deg[dst[e]], 1);
}

__global__ __launch_bounds__(1024) void k_scan(const int* __restrict__ deg, int* __restrict__ off){
  __shared__ int ps[1024];
  int t = threadIdx.x;
  const int CH = (NN + 1023)/1024;   // 20
  int base = t*CH;
  int s = 0;
  for (int i=0;i<CH;i++){ int g=base+i; if (g<NN) s += deg[g]; }
  ps[t] = s; __syncthreads();
  for (int d=1; d<1024; d<<=1){
    int v = (t>=d) ? ps[t-d] : 0;
    __syncthreads();
    ps[t] += v;
    __syncthreads();
  }
  int run = (t==0) ? 0 : ps[t-1];
  for (int i=0;i<CH;i++){ int g=base+i; if (g<NN){ off[g]=run; run += deg[g]; } }
  if (t==1023) off[NN] = run;
}

// fill CSR entries sorted by dst; also record dst node and original edge id
__global__ __launch_bounds__(256) void k_fill(const int* __restrict__ src, const int* __restrict__ dst,
    const int* __restrict__ off, int* __restrict__ cur, int* __restrict__ csr,
    int* __restrict__ dstA, int* __restrict__ eidA){
  int e = blockIdx.x*256 + threadIdx.x;
  if (e < NE){
    int d = dst[e];
    int p = atomicAdd(&cur[d], 1);
    int pos = off[d] + p;
    csr[pos]  = src[e];
    dstA[pos] = d;
    eidA[pos] = e;
  }
}

// ---------------- SAGE mean aggregation (1 wave / node, 4-way ILP) ----------------
__global__ __launch_bounds__(256) void k_aggr(const float* __restrict__ x,
    const int* __restrict__ off, const int* __restrict__ csr, float* __restrict__ agg)
{
  int wid = (blockIdx.x*256 + threadIdx.x) >> 6;
  int lane = threadIdx.x & 63;
  if (wid >= NN) return;
  int b = off[wid], e = off[wid+1];
  float ax0=0.f, ay0=0.f, ax1=0.f, ay1=0.f, ax2=0.f, ay2=0.f, ax3=0.f, ay3=0.f;
  int i = b;
  for (; i+3 < e; i += 4){
    int s0=csr[i], s1=csr[i+1], s2=csr[i+2], s3=csr[i+3];
    float2 v0 = *(const float2*)&x[(size_t)s0*H + lane*2];
    float2 v1 = *(const float2*)&x[(size_t)s1*H + lane*2];
    float2 v2 = *(const float2*)&x[(size_t)s2*H + lane*2];
    float2 v3 = *(const float2*)&x[(size_t)s3*H + lane*2];
    ax0+=v0.x; ay0+=v0.y; ax1+=v1.x; ay1+=v1.y;
    ax2+=v2.x; ay2+=v2.y; ax3+=v3.x; ay3+=v3.y;
  }
  for (; i < e; ++i){
    int s = csr[i];
    float2 v = *(const float2*)&x[(size_t)s*H + lane*2];
    ax0 += v.x; ay0 += v.y;
  }
  float ax = (ax0+ax1)+(ax2+ax3);
  float ay = (ay0+ay1)+(ay2+ay3);
  float inv = 1.0f / fmaxf((float)(e-b), 1.0f);
  *(float2*)&agg[(size_t)wid*H + lane*2] = make_float2(ax*inv, ay*inv);
}

// ---------------- GAT aggregation (float2 lanes, 4-way ILP) ----------------
__global__ __launch_bounds__(256) void k_gat(
    const float* __restrict__ h, const float* __restrict__ hs, const float* __restrict__ hd,
    const int* __restrict__ off, const int* __restrict__ csr,
    const float* __restrict__ bias, float* __restrict__ y)
{
  int wid = (blockIdx.x*256 + threadIdx.x) >> 6;
  int lane = threadIdx.x & 63;
  if (wid >= NN) return;
  int b = off[wid], e = off[wid+1];
  float hdv = hd[wid];
  float eself = lrelu(hs[wid] + hdv);
  float m = eself;
  int i = b;
  for (; i+3 < e; i += 4){
    float l0 = lrelu(hs[csr[i]]   + hdv);
    float l1 = lrelu(hs[csr[i+1]] + hdv);
    float l2 = lrelu(hs[csr[i+2]] + hdv);
    float l3 = lrelu(hs[csr[i+3]] + hdv);
    m = fmaxf(m, fmaxf(fmaxf(l0,l1), fmaxf(l2,l3)));
  }
  for (; i < e; ++i) m = fmaxf(m, lrelu(hs[csr[i]] + hdv));

  float z = expf(eself - m);
  float2 hv = *(const float2*)&h[(size_t)wid*H + lane*2];
  float ax = z*hv.x, ay = z*hv.y;
  i = b;
  for (; i+3 < e; i += 4){
    int s0=csr[i], s1=csr[i+1], s2=csr[i+2], s3=csr[i+3];
    float p0 = expf(lrelu(hs[s0] + hdv) - m);
    float p1 = expf(lrelu(hs[s1] + hdv) - m);
    float p2 = expf(lrelu(hs[s2] + hdv) - m);
    float p3 = expf(lrelu(hs[s3] + hdv) - m);
    z += (p0+p1)+(p2+p3);
    float2 u0 = *(const float2*)&h[(size_t)s0*H + lane*2];
    float2 u1 = *(const float2*)&h[(size_t)s1*H + lane*2];
    float2 u2 = *(const float2*)&h[(size_t)s2*H + lane*2];
    float2 u3 = *(const float2*)&h[(size_t)s3*H + lane*2];
    ax = fmaf(p0,u0.x, fmaf(p1,u1.x, fmaf(p2,u2.x, fmaf(p3,u3.x, ax))));
    ay = fmaf(p0,u0.y, fmaf(p1,u1.y, fmaf(p2,u2.y, fmaf(p3,u3.y, ay))));
  }
  for (; i < e; ++i){
    int s = csr[i];
    float p = expf(lrelu(hs[s] + hdv) - m);
    z += p;
    float2 u = *(const float2*)&h[(size_t)s*H + lane*2];
    ax = fmaf(p, u.x, ax);
    ay = fmaf(p, u.y, ay);
  }
  float inv = 1.0f / z;
  float2 bv = *(const float2*)&bias[lane*2];
  *(float2*)&y[(size_t)wid*H + lane*2] =
      make_float2(fmaxf(ax*inv + bv.x, 0.f), fmaxf(ay*inv + bv.y, 0.f));
}

// ================= shared MFMA machinery (bf16x2 split precision) =================
// Frag (16x16x32): lane l: A[m=l&15][k = kc*32 + (l>>4)*8 + j]; same k bijection
// for B. C: row=(l>>4)*4+r, col=l&15 (m89-verified; passed R4-R6 correctness).
// wcvt layout: matrix m at m*4096 uint4; half hf at +hf*2048; {hi:0, lo:+1024}; [bw*64+s].

// pre-convert 9 weight matrices: 0,1=edgeW; 2..4=sage_Wl; 5..7=sage_Wr; 8=gat_W
__global__ __launch_bounds__(256) void k_wconv_multi(
    const float* __restrict__ edgeW, const float* __restrict__ Wl,
    const float* __restrict__ Wr, const float* __restrict__ gatW,
    uint4* __restrict__ outw)
{
  int t = blockIdx.x*256 + threadIdx.x;       // 0..18431 (9 * 2048)
  int m = t >> 11;
  int r = t & 2047;
  int hf = r >> 10, bw = (r >> 6) & 15, s = r & 63;
  const float* W;
  if      (m < 2) W = edgeW + (size_t)m*16384;
  else if (m < 5) W = Wl    + (size_t)(m-2)*16384;
  else if (m < 8) W = Wr    + (size_t)(m-5)*16384;
  else            W = gatW;
  int row0 = (bw & 3)*32 + (s >> 4)*8;        // kc=bw&3, g=s>>4
  int col  = hf*64 + (bw >> 2)*16 + (s & 15);
  const float* p = W + row0*128 + col;
  float f[8];
  #pragma unroll
  for (int j=0;j<8;j++) f[j] = p[j*128];
  unsigned h0=pk_bf16(f[0],f[1]), h1=pk_bf16(f[2],f[3]),
           h2=pk_bf16(f[4],f[5]), h3=pk_bf16(f[6],f[7]);
  unsigned l0=pk_bf16(f[0]-as_f(h0<<16), f[1]-as_f(h0&0xffff0000u));
  unsigned l1=pk_bf16(f[2]-as_f(h1<<16), f[3]-as_f(h1&0xffff0000u));
  unsigned l2=pk_bf16(f[4]-as_f(h2<<16), f[5]-as_f(h2&0xffff0000u));
  unsigned l3=pk_bf16(f[6]-as_f(h3<<16), f[7]-as_f(h3&0xffff0000u));
  int base = m*4096 + hf*2048;
  outw[base + bw*64 + s]        = make_uint4(h0,h1,h2,h3);
  outw[base + 1024 + bw*64 + s] = make_uint4(l0,l1,l2,l3);
}

// copy one pre-converted 32KB half-layer into LDS (coalesced)
__device__ __forceinline__ void copyW(const uint4* __restrict__ srcw, uint4* R, int tid){
  #pragma unroll
  for (int i=0;i<8;i++) R[tid + i*256] = srcw[tid + i*256];
}

// one column-half of MFMAs: nt = HF*4+ntl, 3 MFMAs per (nt,kc) for bf16x2
template<int HF>
__device__ __forceinline__ void mfma_half(f32x4* acc, const bf16x8* ah, const bf16x8* al,
                                          const uint4* R, int l)
{
  #pragma unroll
  for (int ntl=0; ntl<4; ntl++){
    f32x4 a = acc[HF*4 + ntl];
    #pragma unroll
    for (int kc=0; kc<4; kc++){
      bf16x8 bh = __builtin_bit_cast(bf16x8, R[(ntl*4+kc)*64 + l]);
      bf16x8 bl = __builtin_bit_cast(bf16x8, R[1024 + (ntl*4+kc)*64 + l]);
      a = __builtin_amdgcn_mfma_f32_16x16x32_bf16(ah[kc], bh, a, 0, 0, 0);
      a = __builtin_amdgcn_mfma_f32_16x16x32_bf16(ah[kc], bl, a, 0, 0, 0);
      a = __builtin_amdgcn_mfma_f32_16x16x32_bf16(al[kc], bh, a, 0, 0, 0);
    }
    acc[HF*4 + ntl] = a;
  }
}

// stage 4 A-frags (one row, k=0..127) from global fp32 into bf16 hi/lo regs
__device__ __forceinline__ void stageA(const float* __restrict__ Ap, bool valid, int g8,
                                       bf16x8* ah, bf16x8* al)
{
  #pragma unroll
  for (int kc=0;kc<4;kc++){
    float f[8];
    if (valid){
      float4 u = *(const float4*)&Ap[kc*32 + g8];
      float4 v = *(const float4*)&Ap[kc*32 + g8 + 4];
      f[0]=u.x; f[1]=u.y; f[2]=u.z; f[3]=u.w; f[4]=v.x; f[5]=v.y; f[6]=v.z; f[7]=v.w;
    } else {
      #pragma unroll
      for (int j=0;j<8;j++) f[j]=0.f;
    }
    unsigned hp[4], lp[4];
    #pragma unroll
    for (int q=0;q<4;q++){
      unsigned hh = pk_bf16(f[2*q], f[2*q+1]);
      hp[q] = hh;
      lp[q] = pk_bf16(f[2*q]-as_f(hh<<16), f[2*q+1]-as_f(hh & 0xffff0000u));
    }
    ah[kc] = __builtin_bit_cast(bf16x8, make_uint4(hp[0],hp[1],hp[2],hp[3]));
    al[kc] = __builtin_bit_cast(bf16x8, make_uint4(lp[0],lp[1],lp[2],lp[3]));
  }
}

// ---------------- node GEMM via MFMA: Y = relu(A1@W1 + A2@W2 + b)  |  GAT: h=A1@W, +hs/hd ----------------
template<bool TWO, bool GATEP>
__global__ __launch_bounds__(256) void k_ngemm(
    const float* __restrict__ A1, const float* __restrict__ A2,
    const uint4* __restrict__ wc1, const uint4* __restrict__ wc2,
    const float* __restrict__ bias, float* __restrict__ Y,
    const float* __restrict__ asrc, const float* __restrict__ adst,
    float* __restrict__ hs, float* __restrict__ hd, int M)
{
  __shared__ uint4 R[2048];                   // 32 KB, time-shared for W halves
  const int tid = threadIdx.x;
  const int l = tid & 63, w = tid >> 6;
  const int row0 = blockIdx.x*64;
  const int arow = row0 + w*16 + (l&15);
  const bool avld = arow < M;
  const int g8 = (l>>4)*8;

  bf16x8 ah[4], al[4];
  stageA(A1 + (size_t)arow*H, avld, g8, ah, al);

  f32x4 acc[8];
  #pragma unroll
  for (int i=0;i<8;i++) acc[i] = 0.f;

  copyW(wc1, R, tid); __syncthreads();
  mfma_half<0>(acc, ah, al, R, l);
  __syncthreads(); copyW(wc1 + 2048, R, tid); __syncthreads();
  mfma_half<1>(acc, ah, al, R, l);

  if constexpr (TWO){
    stageA(A2 + (size_t)arow*H, avld, g8, ah, al);
    __syncthreads(); copyW(wc2, R, tid); __syncthreads();
    mfma_half<0>(acc, ah, al, R, l);
    __syncthreads(); copyW(wc2 + 2048, R, tid); __syncthreads();
    mfma_half<1>(acc, ah, al, R, l);
  }

  if constexpr (!GATEP){
    float bv[8];
    #pragma unroll
    for (int nt=0;nt<8;nt++) bv[nt] = bias[nt*16 + (l&15)];
    #pragma unroll
    for (int r=0;r<4;r++){
      int srow = row0 + w*16 + (l>>4)*4 + r;
      if (srow < M){
        #pragma unroll
        for (int nt=0;nt<8;nt++)
          Y[(size_t)srow*H + nt*16 + (l&15)] = fmaxf(acc[nt][r] + bv[nt], 0.f);
      }
    }
  } else {
    float avv[8], dvv[8];
    #pragma unroll
    for (int nt=0;nt<8;nt++){
      avv[nt] = asrc[nt*16 + (l&15)];
      dvv[nt] = adst[nt*16 + (l&15)];
    }
    #pragma unroll
    for (int r=0;r<4;r++){
      int srow = row0 + w*16 + (l>>4)*4 + r;
      float sp = 0.f, dp = 0.f;
      #pragma unroll
      for (int nt=0;nt<8;nt++){
        float hv = acc[nt][r];
        sp = fmaf(hv, avv[nt], sp);
        dp = fmaf(hv, dvv[nt], dp);
        if (srow < M) Y[(size_t)srow*H + nt*16 + (l&15)] = hv;
      }
      #pragma unroll
      for (int mm=1; mm<16; mm<<=1){
        sp += __shfl_xor(sp, mm, 16);
        dp += __shfl_xor(dp, mm, 16);
      }
      if ((l&15)==0 && srow < M){ hs[srow] = sp; hd[srow] = dp; }
    }
  }
}

// ================= MFMA edge MLP — dst-sorted entries + XCD chunk swizzle =================
__global__ __launch_bounds__(256) void k_edge_mfma(
    const float* __restrict__ x, const int* __restrict__ csr, const int* __restrict__ dstA,
    const int* __restrict__ eidA, const uint4* __restrict__ wcvt,
    const float* __restrict__ b1, const float* __restrict__ b2,
    const float* __restrict__ outW, const float* __restrict__ outb,
    float* __restrict__ out)
{
  __shared__ uint4 R[2048];                   // 32 KB, time-shared
  const int tid = threadIdx.x;
  const int l = tid & 63, w = tid >> 6;
  // bijective XCD swizzle: 5000 blocks = 8 XCDs x 625 contiguous chunks
  const int bid = blockIdx.x;
  const int e0 = ((bid & 7)*625 + (bid >> 3)) * 64;

  int eid;
  {
    int i = e0 + l;
    int sn = csr[i], dn = dstA[i];
    eid = eidA[i];
    const float4* ps = (const float4*)(x + (size_t)sn*H + w*32);
    const float4* pd = (const float4*)(x + (size_t)dn*H + w*32);
    float ev[32];
    #pragma unroll
    for (int q=0;q<8;q++){
      float4 a = ps[q], b = pd[q];
      ev[q*4+0]=a.x+b.x; ev[q*4+1]=a.y+b.y; ev[q*4+2]=a.z+b.z; ev[q*4+3]=a.w+b.w;
    }
    int blk = ((l>>4)*4 + w)*64;              // rt*4 + kc
    #pragma unroll
    for (int g=0; g<4; g++){
      unsigned hp[4], lp[4];
      #pragma unroll
      for (int q=0;q<4;q++){
        float f0 = ev[g*8+q*2], f1 = ev[g*8+q*2+1];
        unsigned h = pk_bf16(f0, f1);
        hp[q] = h;
        lp[q] = pk_bf16(f0 - as_f(h<<16), f1 - as_f(h & 0xffff0000u));
      }
      int ai = blk + (l&15) + 16*g;
      R[ai]        = make_uint4(hp[0],hp[1],hp[2],hp[3]);
      R[1024 + ai] = make_uint4(lp[0],lp[1],lp[2],lp[3]);
    }
  }
  __syncthreads();                                       // B1: A1 staged

  bf16x8 ah[4], al[4];
  #pragma unroll
  for (int kc=0; kc<4; kc++){
    ah[kc] = __builtin_bit_cast(bf16x8, R[(w*4+kc)*64 + l]);
    al[kc] = __builtin_bit_cast(bf16x8, R[1024 + (w*4+kc)*64 + l]);
  }
  __syncthreads();                                       // B2: A1 reads done
  copyW(wcvt + 0*2048, R, tid);                          // W1.h0
  __syncthreads();                                       // B3

  f32x4 acc[8];
  #pragma unroll
  for (int i=0;i<8;i++) acc[i] = 0.f;
  mfma_half<0>(acc, ah, al, R, l);
  __syncthreads();                                       // B4
  copyW(wcvt + 1*2048, R, tid);                          // W1.h1
  __syncthreads();                                       // B5
  mfma_half<1>(acc, ah, al, R, l);
  __syncthreads();                                       // B6: W reads done

  {
    float b1v[8];
    #pragma unroll
    for (int nt=0;nt<8;nt++) b1v[nt] = b1[nt*16 + (l&15)];
    #pragma unroll
    for (int nt=0;nt<8;nt++){
      int b2blk = w*4 + (nt>>1);                         // rt2*4 + kc2
      int gp = (2*nt + ((l&15)>>3)) & 3;                 // k-slot group of col
      #pragma unroll
      for (int r=0;r<4;r++){
        float v = fmaxf(acc[nt][r] + b1v[nt], 0.f);
        unsigned h = pk_bf16(v, v);
        unsigned lo = pk_bf16(v - as_f(h<<16), 0.f);
        int sp = (4*(l>>4) + r) + 16*gp;
        int off = (b2blk*64 + sp)*16 + (l&7)*2;
        *(short*)((char*)R + off)         = (short)(h  & 0xffff);
        *(short*)((char*)R + 16384 + off) = (short)(lo & 0xffff);
      }
    }
  }
  #pragma unroll
  for (int kc=0; kc<4; kc++){
    ah[kc] = __builtin_bit_cast(bf16x8, R[(w*4+kc)*64 + l]);
    al[kc] = __builtin_bit_cast(bf16x8, R[1024 + (w*4+kc)*64 + l]);
  }
  __syncthreads();                                       // B7: A2 reads done
  copyW(wcvt + 2*2048, R, tid);                          // W2.h0
  __syncthreads();                                       // B8

  f32x4 acc2[8];
  #pragma unroll
  for (int i=0;i<8;i++) acc2[i] = 0.f;
  mfma_half<0>(acc2, ah, al, R, l);
  __syncthreads();                                       // B9
  copyW(wcvt + 3*2048, R, tid);                          // W2.h1
  __syncthreads();                                       // B10
  mfma_half<1>(acc2, ah, al, R, l);

  {
    float b2v[8], owv[8];
    #pragma unroll
    for (int nt=0;nt<8;nt++){
      b2v[nt] = b2[nt*16 + (l&15)];
      owv[nt] = outW[nt*16 + (l&15)];
    }
    float ob = outb[0];
    #pragma unroll
    for (int r=0;r<4;r++){
      float p = 0.f;
      #pragma unroll
      for (int nt=0;nt<8;nt++)
        p = fmaf(fmaxf(acc2[nt][r] + b2v[nt], 0.f), owv[nt], p);
      #pragma unroll
      for (int m=1;m<16;m<<=1) p += __shfl_xor(p, m, 16);
      int row = w*16 + (l>>4)*4 + r;
      int eo = __shfl(eid, row);               // eid of that output row
      if ((l&15)==0) out[eo] = p + ob;
    }
  }
}

// ---------------- launch ----------------
extern "C" void kernel_launch(void* const* d_in, const int* in_sizes, int n_in,
                              void* d_out, int out_size, void* d_ws, size_t ws_size,
                              hipStream_t stream)
{
  const float* shapes   = (const float*)d_in[0];
  const int*   gate_ids = (const int*)  d_in[1];
  const int*   ei       = (const int*)  d_in[2];
  const float* emb      = (const float*)d_in[3];
  const float* dimW     = (const float*)d_in[4];
  const float* dimb     = (const float*)d_in[5];
  const float* sage_Wl  = (const float*)d_in[6];
  const float* sage_bl  = (const float*)d_in[7];
  const float* sage_Wr  = (const float*)d_in[8];
  const float* gat_W    = (const float*)d_in[9];
  const float* gat_asrc = (const float*)d_in[10];
  const float* gat_adst = (const float*)d_in[11];
  const float* gat_b    = (const float*)d_in[12];
  const float* edgeW    = (const float*)d_in[13];
  const float* edgeb    = (const float*)d_in[14];
  const float* outW     = (const float*)d_in[15];
  const float* outb     = (const float*)d_in[16];
  const int* src = ei;
  const int* dst = ei + NE;

  char* w = (char*)d_ws;
  auto alloc = [&](size_t bytes)->void* {
    void* p = (void*)w; w += (bytes + 255) & ~(size_t)255; return p;
  };
  float* xa   = (float*)alloc((size_t)NN*H*4);
  float* xb   = (float*)alloc((size_t)NN*H*4);
  float* agg  = (float*)alloc((size_t)NN*H*4);
  float* hs   = (float*)alloc((size_t)NN*4);
  float* hd   = (float*)alloc((size_t)NN*4);
  int*   deg  = (int*)alloc((size_t)NN*4);
  int*   off  = (int*)alloc((size_t)(NN+1)*4);
  int*   cur  = (int*)alloc((size_t)NN*4);
  int*   csr  = (int*)alloc((size_t)NE*4);
  int*   dstA = (int*)alloc((size_t)NE*4);
  int*   eidA = (int*)alloc((size_t)NE*4);
  uint4* wcvt = (uint4*)alloc((size_t)9*4096*16);   // 576 KB pre-converted weights

  hipMemsetAsync(deg, 0, (size_t)NN*4, stream);
  hipMemsetAsync(cur, 0, (size_t)NN*4, stream);

  k_node_init<<<(NN*H+255)/256, 256, 0, stream>>>(shapes, gate_ids, emb, dimW, dimb, xa);
  k_count<<<(NE+255)/256, 256, 0, stream>>>(dst, deg);
  k_scan<<<1, 1024, 0, stream>>>(deg, off);
  k_fill<<<(NE+255)/256, 256, 0, stream>>>(src, dst, off, cur, csr, dstA, eidA);
  k_wconv_multi<<<72, 256, 0, stream>>>(edgeW, sage_Wl, sage_Wr, gat_W, wcvt);

  float* xin = xa; float* xout = xb;
  const int gemm_blocks = (NN+63)/64;   // 313
  for (int i=0;i<3;i++){
    k_aggr<<<NN/4, 256, 0, stream>>>(xin, off, csr, agg);
    k_ngemm<true,false><<<gemm_blocks, 256, 0, stream>>>(
        agg, xin, wcvt + (size_t)(2+i)*4096, wcvt + (size_t)(5+i)*4096,
        sage_bl + (size_t)i*H, xout, nullptr, nullptr, nullptr, nullptr, NN);
    float* t = xin; xin = xout; xout = t;
  }

  // GAT: h = x@W (into agg) + per-node hs/hd scalars fused in epilogue
  k_ngemm<false,true><<<gemm_blocks, 256, 0, stream>>>(
      xin, nullptr, wcvt + (size_t)8*4096, nullptr,
      nullptr, agg, gat_asrc, gat_adst, hs, hd, NN);
  k_gat<<<NN/4, 256, 0, stream>>>(agg, hs, hd, off, csr, gat_b, xout);
  { float* t = xin; xin = xout; xout = t; }

  k_edge_mfma<<<NE/64, 256, 0, stream>>>(xout==xa?xb:xa, csr, dstA, eidA, wcvt,
      edgeb, edgeb + H, outW, outb, (float*)d_out);
}

// Round 10
// 399.377 us; speedup vs baseline: 1.9088x; 1.0038x over previous
//
#include <hip/hip_runtime.h>

#define NN 20000
#define NE 320000
#define H  128
#define HH 64

typedef short bf16x8 __attribute__((ext_vector_type(8)));   // 8 bf16 = 4 VGPR
typedef float f32x4  __attribute__((ext_vector_type(4)));

__device__ __forceinline__ float lrelu(float v){ return fmaxf(v, 0.2f*v); }
__device__ __forceinline__ float as_f(unsigned u){ return __uint_as_float(u); }

// packed fp32->bf16 (RNE), 2 floats -> 1 u32 [lo16=cvt(a), hi16=cvt(b)]
__device__ __forceinline__ unsigned pk_bf16(float a, float b){
  unsigned r;
  asm("v_cvt_pk_bf16_f32 %0, %1, %2" : "=v"(r) : "v"(a), "v"(b));
  return r;
}

// ---------------- node feature init ----------------
__global__ __launch_bounds__(256) void k_node_init(
    const float* __restrict__ shapes, const int* __restrict__ gid,
    const float* __restrict__ emb, const float* __restrict__ dimW,
    const float* __restrict__ dimb, float* __restrict__ x)
{
  int idx = blockIdx.x*256 + threadIdx.x;
  if (idx >= NN*H) return;
  int n = idx >> 7, j = idx & 127;
  float v;
  if (j < HH) v = shapes[n]*dimW[j] + dimb[j];
  else        v = emb[gid[n]*HH + (j-HH)];
  x[idx] = v;
}

// ---------------- CSR build ----------------
__global__ __launch_bounds__(256) void k_count(const int* __restrict__ dst, int* __restrict__ deg){
  int e = blockIdx.x*256 + threadIdx.x;
  if (e < NE) atomicAdd(&deg[dst[e]], 1);
}

__global__ __launch_bounds__(1024) void k_scan(const int* __restrict__ deg, int* __restrict__ off){
  __shared__ int ps[1024];
  int t = threadIdx.x;
  const int CH = (NN + 1023)/1024;   // 20
  int base = t*CH;
  int s = 0;
  for (int i=0;i<CH;i++){ int g=base+i; if (g<NN) s += deg[g]; }
  ps[t] = s; __syncthreads();
  for (int d=1; d<1024; d<<=1){
    int v = (t>=d) ? ps[t-d] : 0;
    __syncthreads();
    ps[t] += v;
    __syncthreads();
  }
  int run = (t==0) ? 0 : ps[t-1];
  for (int i=0;i<CH;i++){ int g=base+i; if (g<NN){ off[g]=run; run += deg[g]; } }
  if (t==1023) off[NN] = run;
}

// fill CSR entries sorted by dst; also record dst node and original edge id
__global__ __launch_bounds__(256) void k_fill(const int* __restrict__ src, const int* __restrict__ dst,
    const int* __restrict__ off, int* __restrict__ cur, int* __restrict__ csr,
    int* __restrict__ dstA, int* __restrict__ eidA){
  int e = blockIdx.x*256 + threadIdx.x;
  if (e < NE){
    int d = dst[e];
    int p = atomicAdd(&cur[d], 1);
    int pos = off[d] + p;
    csr[pos]  = src[e];
    dstA[pos] = d;
    eidA[pos] = e;
  }
}

// ---------------- SAGE mean aggregation (1 wave / node, 8-way ILP) ----------------
__global__ __launch_bounds__(256) void k_aggr(const float* __restrict__ x,
    const int* __restrict__ off, const int* __restrict__ csr, float* __restrict__ agg)
{
  int wid = (blockIdx.x*256 + threadIdx.x) >> 6;
  int lane = threadIdx.x & 63;
  if (wid >= NN) return;
  int b = off[wid], e = off[wid+1];
  float ax[8], ay[8];
  #pragma unroll
  for (int q=0;q<8;q++){ ax[q]=0.f; ay[q]=0.f; }
  int i = b;
  for (; i+7 < e; i += 8){
    int s[8];
    #pragma unroll
    for (int q=0;q<8;q++) s[q] = csr[i+q];
    float2 v[8];
    #pragma unroll
    for (int q=0;q<8;q++) v[q] = *(const float2*)&x[(size_t)s[q]*H + lane*2];
    #pragma unroll
    for (int q=0;q<8;q++){ ax[q]+=v[q].x; ay[q]+=v[q].y; }
  }
  for (; i < e; ++i){
    int s = csr[i];
    float2 v = *(const float2*)&x[(size_t)s*H + lane*2];
    ax[0] += v.x; ay[0] += v.y;
  }
  float axs = ((ax[0]+ax[1])+(ax[2]+ax[3])) + ((ax[4]+ax[5])+(ax[6]+ax[7]));
  float ays = ((ay[0]+ay[1])+(ay[2]+ay[3])) + ((ay[4]+ay[5])+(ay[6]+ay[7]));
  float inv = 1.0f / fmaxf((float)(e-b), 1.0f);
  *(float2*)&agg[(size_t)wid*H + lane*2] = make_float2(axs*inv, ays*inv);
}

// ---------------- GAT aggregation (float2 lanes, 8-way ILP) ----------------
__global__ __launch_bounds__(256) void k_gat(
    const float* __restrict__ h, const float* __restrict__ hs, const float* __restrict__ hd,
    const int* __restrict__ off, const int* __restrict__ csr,
    const float* __restrict__ bias, float* __restrict__ y)
{
  int wid = (blockIdx.x*256 + threadIdx.x) >> 6;
  int lane = threadIdx.x & 63;
  if (wid >= NN) return;
  int b = off[wid], e = off[wid+1];
  float hdv = hd[wid];
  float eself = lrelu(hs[wid] + hdv);
  float m = eself;
  int i = b;
  for (; i+7 < e; i += 8){
    float lv[8];
    #pragma unroll
    for (int q=0;q<8;q++) lv[q] = lrelu(hs[csr[i+q]] + hdv);
    float m01 = fmaxf(lv[0],lv[1]), m23 = fmaxf(lv[2],lv[3]);
    float m45 = fmaxf(lv[4],lv[5]), m67 = fmaxf(lv[6],lv[7]);
    m = fmaxf(m, fmaxf(fmaxf(m01,m23), fmaxf(m45,m67)));
  }
  for (; i < e; ++i) m = fmaxf(m, lrelu(hs[csr[i]] + hdv));

  float z = expf(eself - m);
  float2 hv = *(const float2*)&h[(size_t)wid*H + lane*2];
  float ax = z*hv.x, ay = z*hv.y;
  i = b;
  for (; i+7 < e; i += 8){
    int s[8];
    #pragma unroll
    for (int q=0;q<8;q++) s[q] = csr[i+q];
    float p[8];
    #pragma unroll
    for (int q=0;q<8;q++) p[q] = expf(lrelu(hs[s[q]] + hdv) - m);
    float2 u[8];
    #pragma unroll
    for (int q=0;q<8;q++) u[q] = *(const float2*)&h[(size_t)s[q]*H + lane*2];
    z += ((p[0]+p[1])+(p[2]+p[3])) + ((p[4]+p[5])+(p[6]+p[7]));
    #pragma unroll
    for (int q=0;q<8;q++){
      ax = fmaf(p[q], u[q].x, ax);
      ay = fmaf(p[q], u[q].y, ay);
    }
  }
  for (; i < e; ++i){
    int s = csr[i];
    float p = expf(lrelu(hs[s] + hdv) - m);
    z += p;
    float2 u = *(const float2*)&h[(size_t)s*H + lane*2];
    ax = fmaf(p, u.x, ax);
    ay = fmaf(p, u.y, ay);
  }
  float inv = 1.0f / z;
  float2 bv = *(const float2*)&bias[lane*2];
  *(float2*)&y[(size_t)wid*H + lane*2] =
      make_float2(fmaxf(ax*inv + bv.x, 0.f), fmaxf(ay*inv + bv.y, 0.f));
}

// ================= shared MFMA machinery (bf16x2 split precision) =================
// Frag (16x16x32): lane l: A[m=l&15][k = kc*32 + (l>>4)*8 + j]; same k bijection
// for B. C: row=(l>>4)*4+r, col=l&15 (m89-verified; passed R4-R9 correctness).
// wcvt layout: matrix m at m*4096 uint4; half hf at +hf*2048; {hi:0, lo:+1024}; [bw*64+s].

// pre-convert 9 weight matrices: 0,1=edgeW; 2..4=sage_Wl; 5..7=sage_Wr; 8=gat_W
__global__ __launch_bounds__(256) void k_wconv_multi(
    const float* __restrict__ edgeW, const float* __restrict__ Wl,
    const float* __restrict__ Wr, const float* __restrict__ gatW,
    uint4* __restrict__ outw)
{
  int t = blockIdx.x*256 + threadIdx.x;       // 0..18431 (9 * 2048)
  int m = t >> 11;
  int r = t & 2047;
  int hf = r >> 10, bw = (r >> 6) & 15, s = r & 63;
  const float* W;
  if      (m < 2) W = edgeW + (size_t)m*16384;
  else if (m < 5) W = Wl    + (size_t)(m-2)*16384;
  else if (m < 8) W = Wr    + (size_t)(m-5)*16384;
  else            W = gatW;
  int row0 = (bw & 3)*32 + (s >> 4)*8;        // kc=bw&3, g=s>>4
  int col  = hf*64 + (bw >> 2)*16 + (s & 15);
  const float* p = W + row0*128 + col;
  float f[8];
  #pragma unroll
  for (int j=0;j<8;j++) f[j] = p[j*128];
  unsigned h0=pk_bf16(f[0],f[1]), h1=pk_bf16(f[2],f[3]),
           h2=pk_bf16(f[4],f[5]), h3=pk_bf16(f[6],f[7]);
  unsigned l0=pk_bf16(f[0]-as_f(h0<<16), f[1]-as_f(h0&0xffff0000u));
  unsigned l1=pk_bf16(f[2]-as_f(h1<<16), f[3]-as_f(h1&0xffff0000u));
  unsigned l2=pk_bf16(f[4]-as_f(h2<<16), f[5]-as_f(h2&0xffff0000u));
  unsigned l3=pk_bf16(f[6]-as_f(h3<<16), f[7]-as_f(h3&0xffff0000u));
  int base = m*4096 + hf*2048;
  outw[base + bw*64 + s]        = make_uint4(h0,h1,h2,h3);
  outw[base + 1024 + bw*64 + s] = make_uint4(l0,l1,l2,l3);
}

// copy one pre-converted 32KB half-layer into LDS (coalesced)
__device__ __forceinline__ void copyW(const uint4* __restrict__ srcw, uint4* R, int tid){
  #pragma unroll
  for (int i=0;i<8;i++) R[tid + i*256] = srcw[tid + i*256];
}

// one column-half of MFMAs: nt = HF*4+ntl, 3 MFMAs per (nt,kc) for bf16x2
template<int HF>
__device__ __forceinline__ void mfma_half(f32x4* acc, const bf16x8* ah, const bf16x8* al,
                                          const uint4* R, int l)
{
  #pragma unroll
  for (int ntl=0; ntl<4; ntl++){
    f32x4 a = acc[HF*4 + ntl];
    #pragma unroll
    for (int kc=0; kc<4; kc++){
      bf16x8 bh = __builtin_bit_cast(bf16x8, R[(ntl*4+kc)*64 + l]);
      bf16x8 bl = __builtin_bit_cast(bf16x8, R[1024 + (ntl*4+kc)*64 + l]);
      a = __builtin_amdgcn_mfma_f32_16x16x32_bf16(ah[kc], bh, a, 0, 0, 0);
      a = __builtin_amdgcn_mfma_f32_16x16x32_bf16(ah[kc], bl, a, 0, 0, 0);
      a = __builtin_amdgcn_mfma_f32_16x16x32_bf16(al[kc], bh, a, 0, 0, 0);
    }
    acc[HF*4 + ntl] = a;
  }
}

// stage 4 A-frags (one row, k=0..127) from global fp32 into bf16 hi/lo regs
__device__ __forceinline__ void stageA(const float* __restrict__ Ap, bool valid, int g8,
                                       bf16x8* ah, bf16x8* al)
{
  #pragma unroll
  for (int kc=0;kc<4;kc++){
    float f[8];
    if (valid){
      float4 u = *(const float4*)&Ap[kc*32 + g8];
      float4 v = *(const float4*)&Ap[kc*32 + g8 + 4];
      f[0]=u.x; f[1]=u.y; f[2]=u.z; f[3]=u.w; f[4]=v.x; f[5]=v.y; f[6]=v.z; f[7]=v.w;
    } else {
      #pragma unroll
      for (int j=0;j<8;j++) f[j]=0.f;
    }
    unsigned hp[4], lp[4];
    #pragma unroll
    for (int q=0;q<4;q++){
      unsigned hh = pk_bf16(f[2*q], f[2*q+1]);
      hp[q] = hh;
      lp[q] = pk_bf16(f[2*q]-as_f(hh<<16), f[2*q+1]-as_f(hh & 0xffff0000u));
    }
    ah[kc] = __builtin_bit_cast(bf16x8, make_uint4(hp[0],hp[1],hp[2],hp[3]));
    al[kc] = __builtin_bit_cast(bf16x8, make_uint4(lp[0],lp[1],lp[2],lp[3]));
  }
}

// ---------------- node GEMM via MFMA: Y = relu(A1@W1 + A2@W2 + b)  |  GAT: h=A1@W, +hs/hd ----------------
template<bool TWO, bool GATEP>
__global__ __launch_bounds__(256) void k_ngemm(
    const float* __restrict__ A1, const float* __restrict__ A2,
    const uint4* __restrict__ wc1, const uint4* __restrict__ wc2,
    const float* __restrict__ bias, float* __restrict__ Y,
    const float* __restrict__ asrc, const float* __restrict__ adst,
    float* __restrict__ hs, float* __restrict__ hd, int M)
{
  __shared__ uint4 R[2048];                   // 32 KB, time-shared for W halves
  const int tid = threadIdx.x;
  const int l = tid & 63, w = tid >> 6;
  const int row0 = blockIdx.x*64;
  const int arow = row0 + w*16 + (l&15);
  const bool avld = arow < M;
  const int g8 = (l>>4)*8;

  bf16x8 ah[4], al[4];
  stageA(A1 + (size_t)arow*H, avld, g8, ah, al);

  f32x4 acc[8];
  #pragma unroll
  for (int i=0;i<8;i++) acc[i] = 0.f;

  copyW(wc1, R, tid); __syncthreads();
  mfma_half<0>(acc, ah, al, R, l);
  __syncthreads(); copyW(wc1 + 2048, R, tid); __syncthreads();
  mfma_half<1>(acc, ah, al, R, l);

  if constexpr (TWO){
    stageA(A2 + (size_t)arow*H, avld, g8, ah, al);
    __syncthreads(); copyW(wc2, R, tid); __syncthreads();
    mfma_half<0>(acc, ah, al, R, l);
    __syncthreads(); copyW(wc2 + 2048, R, tid); __syncthreads();
    mfma_half<1>(acc, ah, al, R, l);
  }

  if constexpr (!GATEP){
    float bv[8];
    #pragma unroll
    for (int nt=0;nt<8;nt++) bv[nt] = bias[nt*16 + (l&15)];
    #pragma unroll
    for (int r=0;r<4;r++){
      int srow = row0 + w*16 + (l>>4)*4 + r;
      if (srow < M){
        #pragma unroll
        for (int nt=0;nt<8;nt++)
          Y[(size_t)srow*H + nt*16 + (l&15)] = fmaxf(acc[nt][r] + bv[nt], 0.f);
      }
    }
  } else {
    float avv[8], dvv[8];
    #pragma unroll
    for (int nt=0;nt<8;nt++){
      avv[nt] = asrc[nt*16 + (l&15)];
      dvv[nt] = adst[nt*16 + (l&15)];
    }
    #pragma unroll
    for (int r=0;r<4;r++){
      int srow = row0 + w*16 + (l>>4)*4 + r;
      float sp = 0.f, dp = 0.f;
      #pragma unroll
      for (int nt=0;nt<8;nt++){
        float hv = acc[nt][r];
        sp = fmaf(hv, avv[nt], sp);
        dp = fmaf(hv, dvv[nt], dp);
        if (srow < M) Y[(size_t)srow*H + nt*16 + (l&15)] = hv;
      }
      #pragma unroll
      for (int mm=1; mm<16; mm<<=1){
        sp += __shfl_xor(sp, mm, 16);
        dp += __shfl_xor(dp, mm, 16);
      }
      if ((l&15)==0 && srow < M){ hs[srow] = sp; hd[srow] = dp; }
    }
  }
}

// ================= MFMA edge MLP — dst-sorted entries + XCD chunk swizzle =================
__global__ __launch_bounds__(256) void k_edge_mfma(
    const float* __restrict__ x, const int* __restrict__ csr, const int* __restrict__ dstA,
    const int* __restrict__ eidA, const uint4* __restrict__ wcvt,
    const float* __restrict__ b1, const float* __restrict__ b2,
    const float* __restrict__ outW, const float* __restrict__ outb,
    float* __restrict__ out)
{
  __shared__ uint4 R[2048];                   // 32 KB, time-shared
  const int tid = threadIdx.x;
  const int l = tid & 63, w = tid >> 6;
  // bijective XCD swizzle: 5000 blocks = 8 XCDs x 625 contiguous chunks
  const int bid = blockIdx.x;
  const int e0 = ((bid & 7)*625 + (bid >> 3)) * 64;

  int eid;
  {
    int i = e0 + l;
    int sn = csr[i], dn = dstA[i];
    eid = eidA[i];
    const float4* ps = (const float4*)(x + (size_t)sn*H + w*32);
    const float4* pd = (const float4*)(x + (size_t)dn*H + w*32);
    float ev[32];
    #pragma unroll
    for (int q=0;q<8;q++){
      float4 a = ps[q], b = pd[q];
      ev[q*4+0]=a.x+b.x; ev[q*4+1]=a.y+b.y; ev[q*4+2]=a.z+b.z; ev[q*4+3]=a.w+b.w;
    }
    int blk = ((l>>4)*4 + w)*64;              // rt*4 + kc
    #pragma unroll
    for (int g=0; g<4; g++){
      unsigned hp[4], lp[4];
      #pragma unroll
      for (int q=0;q<4;q++){
        float f0 = ev[g*8+q*2], f1 = ev[g*8+q*2+1];
        unsigned h = pk_bf16(f0, f1);
        hp[q] = h;
        lp[q] = pk_bf16(f0 - as_f(h<<16), f1 - as_f(h & 0xffff0000u));
      }
      int ai = blk + (l&15) + 16*g;
      R[ai]        = make_uint4(hp[0],hp[1],hp[2],hp[3]);
      R[1024 + ai] = make_uint4(lp[0],lp[1],lp[2],lp[3]);
    }
  }
  __syncthreads();                                       // B1: A1 staged

  bf16x8 ah[4], al[4];
  #pragma unroll
  for (int kc=0; kc<4; kc++){
    ah[kc] = __builtin_bit_cast(bf16x8, R[(w*4+kc)*64 + l]);
    al[kc] = __builtin_bit_cast(bf16x8, R[1024 + (w*4+kc)*64 + l]);
  }
  __syncthreads();                                       // B2: A1 reads done
  copyW(wcvt + 0*2048, R, tid);                          // W1.h0
  __syncthreads();                                       // B3

  f32x4 acc[8];
  #pragma unroll
  for (int i=0;i<8;i++) acc[i] = 0.f;
  mfma_half<0>(acc, ah, al, R, l);
  __syncthreads();                                       // B4
  copyW(wcvt + 1*2048, R, tid);                          // W1.h1
  __syncthreads();                                       // B5
  mfma_half<1>(acc, ah, al, R, l);
  __syncthreads();                                       // B6: W reads done

  {
    float b1v[8];
    #pragma unroll
    for (int nt=0;nt<8;nt++) b1v[nt] = b1[nt*16 + (l&15)];
    #pragma unroll
    for (int nt=0;nt<8;nt++){
      int b2blk = w*4 + (nt>>1);                         // rt2*4 + kc2
      int gp = (2*nt + ((l&15)>>3)) & 3;                 // k-slot group of col
      #pragma unroll
      for (int r=0;r<4;r++){
        float v = fmaxf(acc[nt][r] + b1v[nt], 0.f);
        unsigned h = pk_bf16(v, v);
        unsigned lo = pk_bf16(v - as_f(h<<16), 0.f);
        int sp = (4*(l>>4) + r) + 16*gp;
        int off = (b2blk*64 + sp)*16 + (l&7)*2;
        *(short*)((char*)R + off)         = (short)(h  & 0xffff);
        *(short*)((char*)R + 16384 + off) = (short)(lo & 0xffff);
      }
    }
  }
  #pragma unroll
  for (int kc=0; kc<4; kc++){
    ah[kc] = __builtin_bit_cast(bf16x8, R[(w*4+kc)*64 + l]);
    al[kc] = __builtin_bit_cast(bf16x8, R[1024 + (w*4+kc)*64 + l]);
  }
  __syncthreads();                                       // B7: A2 reads done
  copyW(wcvt + 2*2048, R, tid);                          // W2.h0
  __syncthreads();                                       // B8

  f32x4 acc2[8];
  #pragma unroll
  for (int i=0;i<8;i++) acc2[i] = 0.f;
  mfma_half<0>(acc2, ah, al, R, l);
  __syncthreads();                                       // B9
  copyW(wcvt + 3*2048, R, tid);                          // W2.h1
  __syncthreads();                                       // B10
  mfma_half<1>(acc2, ah, al, R, l);

  {
    float b2v[8], owv[8];
    #pragma unroll
    for (int nt=0;nt<8;nt++){
      b2v[nt] = b2[nt*16 + (l&15)];
      owv[nt] = outW[nt*16 + (l&15)];
    }
    float ob = outb[0];
    #pragma unroll
    for (int r=0;r<4;r++){
      float p = 0.f;
      #pragma unroll
      for (int nt=0;nt<8;nt++)
        p = fmaf(fmaxf(acc2[nt][r] + b2v[nt], 0.f), owv[nt], p);
      #pragma unroll
      for (int m=1;m<16;m<<=1) p += __shfl_xor(p, m, 16);
      int row = w*16 + (l>>4)*4 + r;
      int eo = __shfl(eid, row);               // eid of that output row
      if ((l&15)==0) out[eo] = p + ob;
    }
  }
}

// ---------------- launch ----------------
extern "C" void kernel_launch(void* const* d_in, const int* in_sizes, int n_in,
                              void* d_out, int out_size, void* d_ws, size_t ws_size,
                              hipStream_t stream)
{
  const float* shapes   = (const float*)d_in[0];
  const int*   gate_ids = (const int*)  d_in[1];
  const int*   ei       = (const int*)  d_in[2];
  const float* emb      = (const float*)d_in[3];
  const float* dimW     = (const float*)d_in[4];
  const float* dimb     = (const float*)d_in[5];
  const float* sage_Wl  = (const float*)d_in[6];
  const float* sage_bl  = (const float*)d_in[7];
  const float* sage_Wr  = (const float*)d_in[8];
  const float* gat_W    = (const float*)d_in[9];
  const float* gat_asrc = (const float*)d_in[10];
  const float* gat_adst = (const float*)d_in[11];
  const float* gat_b    = (const float*)d_in[12];
  const float* edgeW    = (const float*)d_in[13];
  const float* edgeb    = (const float*)d_in[14];
  const float* outW     = (const float*)d_in[15];
  const float* outb     = (const float*)d_in[16];
  const int* src = ei;
  const int* dst = ei + NE;

  char* w = (char*)d_ws;
  auto alloc = [&](size_t bytes)->void* {
    void* p = (void*)w; w += (bytes + 255) & ~(size_t)255; return p;
  };
  float* xa   = (float*)alloc((size_t)NN*H*4);
  float* xb   = (float*)alloc((size_t)NN*H*4);
  float* agg  = (float*)alloc((size_t)NN*H*4);
  float* hs   = (float*)alloc((size_t)NN*4);
  float* hd   = (float*)alloc((size_t)NN*4);
  int*   deg  = (int*)alloc((size_t)NN*4);
  int*   off  = (int*)alloc((size_t)(NN+1)*4);
  int*   cur  = (int*)alloc((size_t)NN*4);
  int*   csr  = (int*)alloc((size_t)NE*4);
  int*   dstA = (int*)alloc((size_t)NE*4);
  int*   eidA = (int*)alloc((size_t)NE*4);
  uint4* wcvt = (uint4*)alloc((size_t)9*4096*16);   // 576 KB pre-converted weights

  hipMemsetAsync(deg, 0, (size_t)NN*4, stream);
  hipMemsetAsync(cur, 0, (size_t)NN*4, stream);

  k_node_init<<<(NN*H+255)/256, 256, 0, stream>>>(shapes, gate_ids, emb, dimW, dimb, xa);
  k_count<<<(NE+255)/256, 256, 0, stream>>>(dst, deg);
  k_scan<<<1, 1024, 0, stream>>>(deg, off);
  k_fill<<<(NE+255)/256, 256, 0, stream>>>(src, dst, off, cur, csr, dstA, eidA);
  k_wconv_multi<<<72, 256, 0, stream>>>(edgeW, sage_Wl, sage_Wr, gat_W, wcvt);

  float* xin = xa; float* xout = xb;
  const int gemm_blocks = (NN+63)/64;   // 313
  for (int i=0;i<3;i++){
    k_aggr<<<NN/4, 256, 0, stream>>>(xin, off, csr, agg);
    k_ngemm<true,false><<<gemm_blocks, 256, 0, stream>>>(
        agg, xin, wcvt + (size_t)(2+i)*4096, wcvt + (size_t)(5+i)*4096,
        sage_bl + (size_t)i*H, xout, nullptr, nullptr, nullptr, nullptr, NN);
    float* t = xin; xin = xout; xout = t;
  }

  // GAT: h = x@W (into agg) + per-node hs/hd scalars fused in epilogue
  k_ngemm<false,true><<<gemm_blocks, 256, 0, stream>>>(
      xin, nullptr, wcvt + (size_t)8*4096, nullptr,
      nullptr, agg, gat_asrc, gat_adst, hs, hd, NN);
  k_gat<<<NN/4, 256, 0, stream>>>(agg, hs, hd, off, csr, gat_b, xout);
  { float* t = xin; xin = xout; xout = t; }

  k_edge_mfma<<<NE/64, 256, 0, stream>>>(xout==xa?xb:xa, csr, dstA, eidA, wcvt,
      edgeb, edgeb + H, outW, outb, (float*)d_out);
}

// Round 11
// 388.302 us; speedup vs baseline: 1.9632x; 1.0285x over previous
//
#include <hip/hip_runtime.h>

#define NN 20000
#define NE 320000
#define H  128
#define HH 64

typedef short bf16x8 __attribute__((ext_vector_type(8)));   // 8 bf16 = 4 VGPR
typedef float f32x4  __attribute__((ext_vector_type(4)));

__device__ __forceinline__ float lrelu(float v){ return fmaxf(v, 0.2f*v); }
__device__ __forceinline__ float as_f(unsigned u){ return __uint_as_float(u); }

// packed fp32->bf16 (RNE), 2 floats -> 1 u32 [lo16=cvt(a), hi16=cvt(b)]
__device__ __forceinline__ unsigned pk_bf16(float a, float b){
  unsigned r;
  asm("v_cvt_pk_bf16_f32 %0, %1, %2" : "=v"(r) : "v"(a), "v"(b));
  return r;
}

// ---------------- node feature init ----------------
__global__ __launch_bounds__(256) void k_node_init(
    const float* __restrict__ shapes, const int* __restrict__ gid,
    const float* __restrict__ emb, const float* __restrict__ dimW,
    const float* __restrict__ dimb, float* __restrict__ x)
{
  int idx = blockIdx.x*256 + threadIdx.x;
  if (idx >= NN*H) return;
  int n = idx >> 7, j = idx & 127;
  float v;
  if (j < HH) v = shapes[n]*dimW[j] + dimb[j];
  else        v = emb[gid[n]*HH + (j-HH)];
  x[idx] = v;
}

// ---------------- CSR build ----------------
__global__ __launch_bounds__(256) void k_count(const int* __restrict__ dst, int* __restrict__ deg){
  int e = blockIdx.x*256 + threadIdx.x;
  if (e < NE) atomicAdd(&deg[dst[e]], 1);
}

__global__ __launch_bounds__(1024) void k_scan(const int* __restrict__ deg, int* __restrict__ off){
  __shared__ int ps[1024];
  int t = threadIdx.x;
  const int CH = (NN + 1023)/1024;   // 20
  int base = t*CH;
  int s = 0;
  for (int i=0;i<CH;i++){ int g=base+i; if (g<NN) s += deg[g]; }
  ps[t] = s; __syncthreads();
  for (int d=1; d<1024; d<<=1){
    int v = (t>=d) ? ps[t-d] : 0;
    __syncthreads();
    ps[t] += v;
    __syncthreads();
  }
  int run = (t==0) ? 0 : ps[t-1];
  for (int i=0;i<CH;i++){ int g=base+i; if (g<NN){ off[g]=run; run += deg[g]; } }
  if (t==1023) off[NN] = run;
}

// fill CSR entries sorted by dst; also record dst node and original edge id
__global__ __launch_bounds__(256) void k_fill(const int* __restrict__ src, const int* __restrict__ dst,
    const int* __restrict__ off, int* __restrict__ cur, int* __restrict__ csr,
    int* __restrict__ dstA, int* __restrict__ eidA){
  int e = blockIdx.x*256 + threadIdx.x;
  if (e < NE){
    int d = dst[e];
    int p = atomicAdd(&cur[d], 1);
    int pos = off[d] + p;
    csr[pos]  = src[e];
    dstA[pos] = d;
    eidA[pos] = e;
  }
}

// ---------------- SAGE mean aggregation (1 wave / node, float4 x 2 rows/instr) ----------------
// lanes 0-31 handle even-list edges, lanes 32-63 odd-list edges; lane covers 4 features.
__global__ __launch_bounds__(256) void k_aggr(const float* __restrict__ x,
    const int* __restrict__ off, const int* __restrict__ csr, float* __restrict__ agg)
{
  int wid = (blockIdx.x*256 + threadIdx.x) >> 6;
  int lane = threadIdx.x & 63;
  if (wid >= NN) return;
  int half = lane >> 5;        // 0 or 1
  int f0 = (lane & 31) * 4;    // feature base
  int b = off[wid], e = off[wid+1];

  float4 a0 = make_float4(0.f,0.f,0.f,0.f), a1 = a0, a2 = a0, a3 = a0;
  int i = b;
  for (; i+7 < e; i += 8){
    int s0 = csr[i     + half];
    int s1 = csr[i + 2 + half];
    int s2 = csr[i + 4 + half];
    int s3 = csr[i + 6 + half];
    float4 v0 = *(const float4*)&x[(size_t)s0*H + f0];
    float4 v1 = *(const float4*)&x[(size_t)s1*H + f0];
    float4 v2 = *(const float4*)&x[(size_t)s2*H + f0];
    float4 v3 = *(const float4*)&x[(size_t)s3*H + f0];
    a0.x+=v0.x; a0.y+=v0.y; a0.z+=v0.z; a0.w+=v0.w;
    a1.x+=v1.x; a1.y+=v1.y; a1.z+=v1.z; a1.w+=v1.w;
    a2.x+=v2.x; a2.y+=v2.y; a2.z+=v2.z; a2.w+=v2.w;
    a3.x+=v3.x; a3.y+=v3.y; a3.z+=v3.z; a3.w+=v3.w;
  }
  for (; i+1 < e; i += 2){
    int s = csr[i + half];
    float4 v = *(const float4*)&x[(size_t)s*H + f0];
    a0.x+=v.x; a0.y+=v.y; a0.z+=v.z; a0.w+=v.w;
  }
  if (i < e && half == 0){
    int s = csr[i];
    float4 v = *(const float4*)&x[(size_t)s*H + f0];
    a0.x+=v.x; a0.y+=v.y; a0.z+=v.z; a0.w+=v.w;
  }
  float4 t;
  t.x = (a0.x+a1.x)+(a2.x+a3.x);
  t.y = (a0.y+a1.y)+(a2.y+a3.y);
  t.z = (a0.z+a1.z)+(a2.z+a3.z);
  t.w = (a0.w+a1.w)+(a2.w+a3.w);
  t.x += __shfl_xor(t.x, 32);
  t.y += __shfl_xor(t.y, 32);
  t.z += __shfl_xor(t.z, 32);
  t.w += __shfl_xor(t.w, 32);
  float inv = 1.0f / fmaxf((float)(e-b), 1.0f);
  if (half == 0)
    *(float4*)&agg[(size_t)wid*H + f0] = make_float4(t.x*inv, t.y*inv, t.z*inv, t.w*inv);
}

// ---------------- GAT aggregation (float4 x 2 rows/instr) ----------------
__global__ __launch_bounds__(256) void k_gat(
    const float* __restrict__ h, const float* __restrict__ hs, const float* __restrict__ hd,
    const int* __restrict__ off, const int* __restrict__ csr,
    const float* __restrict__ bias, float* __restrict__ y)
{
  int wid = (blockIdx.x*256 + threadIdx.x) >> 6;
  int lane = threadIdx.x & 63;
  if (wid >= NN) return;
  int half = lane >> 5;
  int f0 = (lane & 31) * 4;
  int b = off[wid], e = off[wid+1];
  float hdv = hd[wid];
  float eself = lrelu(hs[wid] + hdv);

  // pass 1: max (uniform scalar gather, 8-way ILP)
  float m = eself;
  int i = b;
  for (; i+7 < e; i += 8){
    float lv[8];
    #pragma unroll
    for (int q=0;q<8;q++) lv[q] = lrelu(hs[csr[i+q]] + hdv);
    float m01 = fmaxf(lv[0],lv[1]), m23 = fmaxf(lv[2],lv[3]);
    float m45 = fmaxf(lv[4],lv[5]), m67 = fmaxf(lv[6],lv[7]);
    m = fmaxf(m, fmaxf(fmaxf(m01,m23), fmaxf(m45,m67)));
  }
  for (; i < e; ++i) m = fmaxf(m, lrelu(hs[csr[i]] + hdv));

  // pass 2: weighted sum, 2 rows per instruction
  float zk = 0.f;
  float4 acc = make_float4(0.f,0.f,0.f,0.f);
  i = b;
  for (; i+7 < e; i += 8){
    int s0 = csr[i     + half];
    int s1 = csr[i + 2 + half];
    int s2 = csr[i + 4 + half];
    int s3 = csr[i + 6 + half];
    float p0 = expf(lrelu(hs[s0] + hdv) - m);
    float p1 = expf(lrelu(hs[s1] + hdv) - m);
    float p2 = expf(lrelu(hs[s2] + hdv) - m);
    float p3 = expf(lrelu(hs[s3] + hdv) - m);
    float4 v0 = *(const float4*)&h[(size_t)s0*H + f0];
    float4 v1 = *(const float4*)&h[(size_t)s1*H + f0];
    float4 v2 = *(const float4*)&h[(size_t)s2*H + f0];
    float4 v3 = *(const float4*)&h[(size_t)s3*H + f0];
    zk += (p0+p1)+(p2+p3);
    acc.x = fmaf(p0,v0.x, fmaf(p1,v1.x, fmaf(p2,v2.x, fmaf(p3,v3.x, acc.x))));
    acc.y = fmaf(p0,v0.y, fmaf(p1,v1.y, fmaf(p2,v2.y, fmaf(p3,v3.y, acc.y))));
    acc.z = fmaf(p0,v0.z, fmaf(p1,v1.z, fmaf(p2,v2.z, fmaf(p3,v3.z, acc.z))));
    acc.w = fmaf(p0,v0.w, fmaf(p1,v1.w, fmaf(p2,v2.w, fmaf(p3,v3.w, acc.w))));
  }
  for (; i+1 < e; i += 2){
    int s = csr[i + half];
    float p = expf(lrelu(hs[s] + hdv) - m);
    float4 v = *(const float4*)&h[(size_t)s*H + f0];
    zk += p;
    acc.x = fmaf(p,v.x,acc.x); acc.y = fmaf(p,v.y,acc.y);
    acc.z = fmaf(p,v.z,acc.z); acc.w = fmaf(p,v.w,acc.w);
  }
  if (i < e && half == 0){
    int s = csr[i];
    float p = expf(lrelu(hs[s] + hdv) - m);
    float4 v = *(const float4*)&h[(size_t)s*H + f0];
    zk += p;
    acc.x = fmaf(p,v.x,acc.x); acc.y = fmaf(p,v.y,acc.y);
    acc.z = fmaf(p,v.z,acc.z); acc.w = fmaf(p,v.w,acc.w);
  }
  zk    += __shfl_xor(zk, 32);
  acc.x += __shfl_xor(acc.x, 32);
  acc.y += __shfl_xor(acc.y, 32);
  acc.z += __shfl_xor(acc.z, 32);
  acc.w += __shfl_xor(acc.w, 32);

  float es = expf(eself - m);
  float z = es + zk;
  float inv = 1.0f / z;
  if (half == 0){
    float4 hv = *(const float4*)&h[(size_t)wid*H + f0];
    float4 bv = *(const float4*)&bias[f0];
    float4 o;
    o.x = fmaxf((fmaf(es,hv.x,acc.x))*inv + bv.x, 0.f);
    o.y = fmaxf((fmaf(es,hv.y,acc.y))*inv + bv.y, 0.f);
    o.z = fmaxf((fmaf(es,hv.z,acc.z))*inv + bv.z, 0.f);
    o.w = fmaxf((fmaf(es,hv.w,acc.w))*inv + bv.w, 0.f);
    *(float4*)&y[(size_t)wid*H + f0] = o;
  }
}

// ================= shared MFMA machinery (bf16x2 split precision) =================
// Frag (16x16x32): lane l: A[m=l&15][k = kc*32 + (l>>4)*8 + j]; same k bijection
// for B. C: row=(l>>4)*4+r, col=l&15 (m89-verified; passed R4-R10 correctness).
// wcvt layout: matrix m at m*4096 uint4; half hf at +hf*2048; {hi:0, lo:+1024}; [bw*64+s].

// pre-convert 9 weight matrices: 0,1=edgeW; 2..4=sage_Wl; 5..7=sage_Wr; 8=gat_W
__global__ __launch_bounds__(256) void k_wconv_multi(
    const float* __restrict__ edgeW, const float* __restrict__ Wl,
    const float* __restrict__ Wr, const float* __restrict__ gatW,
    uint4* __restrict__ outw)
{
  int t = blockIdx.x*256 + threadIdx.x;       // 0..18431 (9 * 2048)
  int m = t >> 11;
  int r = t & 2047;
  int hf = r >> 10, bw = (r >> 6) & 15, s = r & 63;
  const float* W;
  if      (m < 2) W = edgeW + (size_t)m*16384;
  else if (m < 5) W = Wl    + (size_t)(m-2)*16384;
  else if (m < 8) W = Wr    + (size_t)(m-5)*16384;
  else            W = gatW;
  int row0 = (bw & 3)*32 + (s >> 4)*8;        // kc=bw&3, g=s>>4
  int col  = hf*64 + (bw >> 2)*16 + (s & 15);
  const float* p = W + row0*128 + col;
  float f[8];
  #pragma unroll
  for (int j=0;j<8;j++) f[j] = p[j*128];
  unsigned h0=pk_bf16(f[0],f[1]), h1=pk_bf16(f[2],f[3]),
           h2=pk_bf16(f[4],f[5]), h3=pk_bf16(f[6],f[7]);
  unsigned l0=pk_bf16(f[0]-as_f(h0<<16), f[1]-as_f(h0&0xffff0000u));
  unsigned l1=pk_bf16(f[2]-as_f(h1<<16), f[3]-as_f(h1&0xffff0000u));
  unsigned l2=pk_bf16(f[4]-as_f(h2<<16), f[5]-as_f(h2&0xffff0000u));
  unsigned l3=pk_bf16(f[6]-as_f(h3<<16), f[7]-as_f(h3&0xffff0000u));
  int base = m*4096 + hf*2048;
  outw[base + bw*64 + s]        = make_uint4(h0,h1,h2,h3);
  outw[base + 1024 + bw*64 + s] = make_uint4(l0,l1,l2,l3);
}

// copy one pre-converted 32KB half-layer into LDS (coalesced)
__device__ __forceinline__ void copyW(const uint4* __restrict__ srcw, uint4* R, int tid){
  #pragma unroll
  for (int i=0;i<8;i++) R[tid + i*256] = srcw[tid + i*256];
}

// one column-half of MFMAs: nt = HF*4+ntl, 3 MFMAs per (nt,kc) for bf16x2
template<int HF>
__device__ __forceinline__ void mfma_half(f32x4* acc, const bf16x8* ah, const bf16x8* al,
                                          const uint4* R, int l)
{
  #pragma unroll
  for (int ntl=0; ntl<4; ntl++){
    f32x4 a = acc[HF*4 + ntl];
    #pragma unroll
    for (int kc=0; kc<4; kc++){
      bf16x8 bh = __builtin_bit_cast(bf16x8, R[(ntl*4+kc)*64 + l]);
      bf16x8 bl = __builtin_bit_cast(bf16x8, R[1024 + (ntl*4+kc)*64 + l]);
      a = __builtin_amdgcn_mfma_f32_16x16x32_bf16(ah[kc], bh, a, 0, 0, 0);
      a = __builtin_amdgcn_mfma_f32_16x16x32_bf16(ah[kc], bl, a, 0, 0, 0);
      a = __builtin_amdgcn_mfma_f32_16x16x32_bf16(al[kc], bh, a, 0, 0, 0);
    }
    acc[HF*4 + ntl] = a;
  }
}

// stage 4 A-frags (one row, k=0..127) from global fp32 into bf16 hi/lo regs
__device__ __forceinline__ void stageA(const float* __restrict__ Ap, bool valid, int g8,
                                       bf16x8* ah, bf16x8* al)
{
  #pragma unroll
  for (int kc=0;kc<4;kc++){
    float f[8];
    if (valid){
      float4 u = *(const float4*)&Ap[kc*32 + g8];
      float4 v = *(const float4*)&Ap[kc*32 + g8 + 4];
      f[0]=u.x; f[1]=u.y; f[2]=u.z; f[3]=u.w; f[4]=v.x; f[5]=v.y; f[6]=v.z; f[7]=v.w;
    } else {
      #pragma unroll
      for (int j=0;j<8;j++) f[j]=0.f;
    }
    unsigned hp[4], lp[4];
    #pragma unroll
    for (int q=0;q<4;q++){
      unsigned hh = pk_bf16(f[2*q], f[2*q+1]);
      hp[q] = hh;
      lp[q] = pk_bf16(f[2*q]-as_f(hh<<16), f[2*q+1]-as_f(hh & 0xffff0000u));
    }
    ah[kc] = __builtin_bit_cast(bf16x8, make_uint4(hp[0],hp[1],hp[2],hp[3]));
    al[kc] = __builtin_bit_cast(bf16x8, make_uint4(lp[0],lp[1],lp[2],lp[3]));
  }
}

// ---------------- node GEMM via MFMA: Y = relu(A1@W1 + A2@W2 + b)  |  GAT: h=A1@W, +hs/hd ----------------
template<bool TWO, bool GATEP>
__global__ __launch_bounds__(256) void k_ngemm(
    const float* __restrict__ A1, const float* __restrict__ A2,
    const uint4* __restrict__ wc1, const uint4* __restrict__ wc2,
    const float* __restrict__ bias, float* __restrict__ Y,
    const float* __restrict__ asrc, const float* __restrict__ adst,
    float* __restrict__ hs, float* __restrict__ hd, int M)
{
  __shared__ uint4 R[2048];                   // 32 KB, time-shared for W halves
  const int tid = threadIdx.x;
  const int l = tid & 63, w = tid >> 6;
  const int row0 = blockIdx.x*64;
  const int arow = row0 + w*16 + (l&15);
  const bool avld = arow < M;
  const int g8 = (l>>4)*8;

  bf16x8 ah[4], al[4];
  stageA(A1 + (size_t)arow*H, avld, g8, ah, al);

  f32x4 acc[8];
  #pragma unroll
  for (int i=0;i<8;i++) acc[i] = 0.f;

  copyW(wc1, R, tid); __syncthreads();
  mfma_half<0>(acc, ah, al, R, l);
  __syncthreads(); copyW(wc1 + 2048, R, tid); __syncthreads();
  mfma_half<1>(acc, ah, al, R, l);

  if constexpr (TWO){
    stageA(A2 + (size_t)arow*H, avld, g8, ah, al);
    __syncthreads(); copyW(wc2, R, tid); __syncthreads();
    mfma_half<0>(acc, ah, al, R, l);
    __syncthreads(); copyW(wc2 + 2048, R, tid); __syncthreads();
    mfma_half<1>(acc, ah, al, R, l);
  }

  if constexpr (!GATEP){
    float bv[8];
    #pragma unroll
    for (int nt=0;nt<8;nt++) bv[nt] = bias[nt*16 + (l&15)];
    #pragma unroll
    for (int r=0;r<4;r++){
      int srow = row0 + w*16 + (l>>4)*4 + r;
      if (srow < M){
        #pragma unroll
        for (int nt=0;nt<8;nt++)
          Y[(size_t)srow*H + nt*16 + (l&15)] = fmaxf(acc[nt][r] + bv[nt], 0.f);
      }
    }
  } else {
    float avv[8], dvv[8];
    #pragma unroll
    for (int nt=0;nt<8;nt++){
      avv[nt] = asrc[nt*16 + (l&15)];
      dvv[nt] = adst[nt*16 + (l&15)];
    }
    #pragma unroll
    for (int r=0;r<4;r++){
      int srow = row0 + w*16 + (l>>4)*4 + r;
      float sp = 0.f, dp = 0.f;
      #pragma unroll
      for (int nt=0;nt<8;nt++){
        float hv = acc[nt][r];
        sp = fmaf(hv, avv[nt], sp);
        dp = fmaf(hv, dvv[nt], dp);
        if (srow < M) Y[(size_t)srow*H + nt*16 + (l&15)] = hv;
      }
      #pragma unroll
      for (int mm=1; mm<16; mm<<=1){
        sp += __shfl_xor(sp, mm, 16);
        dp += __shfl_xor(dp, mm, 16);
      }
      if ((l&15)==0 && srow < M){ hs[srow] = sp; hd[srow] = dp; }
    }
  }
}

// ================= MFMA edge MLP — dst-sorted entries + XCD chunk swizzle =================
__global__ __launch_bounds__(256) void k_edge_mfma(
    const float* __restrict__ x, const int* __restrict__ csr, const int* __restrict__ dstA,
    const int* __restrict__ eidA, const uint4* __restrict__ wcvt,
    const float* __restrict__ b1, const float* __restrict__ b2,
    const float* __restrict__ outW, const float* __restrict__ outb,
    float* __restrict__ out)
{
  __shared__ uint4 R[2048];                   // 32 KB, time-shared
  const int tid = threadIdx.x;
  const int l = tid & 63, w = tid >> 6;
  // bijective XCD swizzle: 5000 blocks = 8 XCDs x 625 contiguous chunks
  const int bid = blockIdx.x;
  const int e0 = ((bid & 7)*625 + (bid >> 3)) * 64;

  int eid;
  {
    int i = e0 + l;
    int sn = csr[i], dn = dstA[i];
    eid = eidA[i];
    const float4* ps = (const float4*)(x + (size_t)sn*H + w*32);
    const float4* pd = (const float4*)(x + (size_t)dn*H + w*32);
    float ev[32];
    #pragma unroll
    for (int q=0;q<8;q++){
      float4 a = ps[q], b = pd[q];
      ev[q*4+0]=a.x+b.x; ev[q*4+1]=a.y+b.y; ev[q*4+2]=a.z+b.z; ev[q*4+3]=a.w+b.w;
    }
    int blk = ((l>>4)*4 + w)*64;              // rt*4 + kc
    #pragma unroll
    for (int g=0; g<4; g++){
      unsigned hp[4], lp[4];
      #pragma unroll
      for (int q=0;q<4;q++){
        float f0 = ev[g*8+q*2], f1 = ev[g*8+q*2+1];
        unsigned h = pk_bf16(f0, f1);
        hp[q] = h;
        lp[q] = pk_bf16(f0 - as_f(h<<16), f1 - as_f(h & 0xffff0000u));
      }
      int ai = blk + (l&15) + 16*g;
      R[ai]        = make_uint4(hp[0],hp[1],hp[2],hp[3]);
      R[1024 + ai] = make_uint4(lp[0],lp[1],lp[2],lp[3]);
    }
  }
  __syncthreads();                                       // B1: A1 staged

  bf16x8 ah[4], al[4];
  #pragma unroll
  for (int kc=0; kc<4; kc++){
    ah[kc] = __builtin_bit_cast(bf16x8, R[(w*4+kc)*64 + l]);
    al[kc] = __builtin_bit_cast(bf16x8, R[1024 + (w*4+kc)*64 + l]);
  }
  __syncthreads();                                       // B2: A1 reads done
  copyW(wcvt + 0*2048, R, tid);                          // W1.h0
  __syncthreads();                                       // B3

  f32x4 acc[8];
  #pragma unroll
  for (int i=0;i<8;i++) acc[i] = 0.f;
  mfma_half<0>(acc, ah, al, R, l);
  __syncthreads();                                       // B4
  copyW(wcvt + 1*2048, R, tid);                          // W1.h1
  __syncthreads();                                       // B5
  mfma_half<1>(acc, ah, al, R, l);
  __syncthreads();                                       // B6: W reads done

  {
    float b1v[8];
    #pragma unroll
    for (int nt=0;nt<8;nt++) b1v[nt] = b1[nt*16 + (l&15)];
    #pragma unroll
    for (int nt=0;nt<8;nt++){
      int b2blk = w*4 + (nt>>1);                         // rt2*4 + kc2
      int gp = (2*nt + ((l&15)>>3)) & 3;                 // k-slot group of col
      #pragma unroll
      for (int r=0;r<4;r++){
        float v = fmaxf(acc[nt][r] + b1v[nt], 0.f);
        unsigned h = pk_bf16(v, v);
        unsigned lo = pk_bf16(v - as_f(h<<16), 0.f);
        int sp = (4*(l>>4) + r) + 16*gp;
        int off = (b2blk*64 + sp)*16 + (l&7)*2;
        *(short*)((char*)R + off)         = (short)(h  & 0xffff);
        *(short*)((char*)R + 16384 + off) = (short)(lo & 0xffff);
      }
    }
  }
  #pragma unroll
  for (int kc=0; kc<4; kc++){
    ah[kc] = __builtin_bit_cast(bf16x8, R[(w*4+kc)*64 + l]);
    al[kc] = __builtin_bit_cast(bf16x8, R[1024 + (w*4+kc)*64 + l]);
  }
  __syncthreads();                                       // B7: A2 reads done
  copyW(wcvt + 2*2048, R, tid);                          // W2.h0
  __syncthreads();                                       // B8

  f32x4 acc2[8];
  #pragma unroll
  for (int i=0;i<8;i++) acc2[i] = 0.f;
  mfma_half<0>(acc2, ah, al, R, l);
  __syncthreads();                                       // B9
  copyW(wcvt + 3*2048, R, tid);                          // W2.h1
  __syncthreads();                                       // B10
  mfma_half<1>(acc2, ah, al, R, l);

  {
    float b2v[8], owv[8];
    #pragma unroll
    for (int nt=0;nt<8;nt++){
      b2v[nt] = b2[nt*16 + (l&15)];
      owv[nt] = outW[nt*16 + (l&15)];
    }
    float ob = outb[0];
    #pragma unroll
    for (int r=0;r<4;r++){
      float p = 0.f;
      #pragma unroll
      for (int nt=0;nt<8;nt++)
        p = fmaf(fmaxf(acc2[nt][r] + b2v[nt], 0.f), owv[nt], p);
      #pragma unroll
      for (int m=1;m<16;m<<=1) p += __shfl_xor(p, m, 16);
      int row = w*16 + (l>>4)*4 + r;
      int eo = __shfl(eid, row);               // eid of that output row
      if ((l&15)==0) out[eo] = p + ob;
    }
  }
}

// ---------------- launch ----------------
extern "C" void kernel_launch(void* const* d_in, const int* in_sizes, int n_in,
                              void* d_out, int out_size, void* d_ws, size_t ws_size,
                              hipStream_t stream)
{
  const float* shapes   = (const float*)d_in[0];
  const int*   gate_ids = (const int*)  d_in[1];
  const int*   ei       = (const int*)  d_in[2];
  const float* emb      = (const float*)d_in[3];
  const float* dimW     = (const float*)d_in[4];
  const float* dimb     = (const float*)d_in[5];
  const float* sage_Wl  = (const float*)d_in[6];
  const float* sage_bl  = (const float*)d_in[7];
  const float* sage_Wr  = (const float*)d_in[8];
  const float* gat_W    = (const float*)d_in[9];
  const float* gat_asrc = (const float*)d_in[10];
  const float* gat_adst = (const float*)d_in[11];
  const float* gat_b    = (const float*)d_in[12];
  const float* edgeW    = (const float*)d_in[13];
  const float* edgeb    = (const float*)d_in[14];
  const float* outW     = (const float*)d_in[15];
  const float* outb     = (const float*)d_in[16];
  const int* src = ei;
  const int* dst = ei + NE;

  char* w = (char*)d_ws;
  auto alloc = [&](size_t bytes)->void* {
    void* p = (void*)w; w += (bytes + 255) & ~(size_t)255; return p;
  };
  float* xa   = (float*)alloc((size_t)NN*H*4);
  float* xb   = (float*)alloc((size_t)NN*H*4);
  float* agg  = (float*)alloc((size_t)NN*H*4);
  float* hs   = (float*)alloc((size_t)NN*4);
  float* hd   = (float*)alloc((size_t)NN*4);
  int*   deg  = (int*)alloc((size_t)NN*4);
  int*   off  = (int*)alloc((size_t)(NN+1)*4);
  int*   cur  = (int*)alloc((size_t)NN*4);
  int*   csr  = (int*)alloc((size_t)NE*4);
  int*   dstA = (int*)alloc((size_t)NE*4);
  int*   eidA = (int*)alloc((size_t)NE*4);
  uint4* wcvt = (uint4*)alloc((size_t)9*4096*16);   // 576 KB pre-converted weights

  hipMemsetAsync(deg, 0, (size_t)NN*4, stream);
  hipMemsetAsync(cur, 0, (size_t)NN*4, stream);

  k_node_init<<<(NN*H+255)/256, 256, 0, stream>>>(shapes, gate_ids, emb, dimW, dimb, xa);
  k_count<<<(NE+255)/256, 256, 0, stream>>>(dst, deg);
  k_scan<<<1, 1024, 0, stream>>>(deg, off);
  k_fill<<<(NE+255)/256, 256, 0, stream>>>(src, dst, off, cur, csr, dstA, eidA);
  k_wconv_multi<<<72, 256, 0, stream>>>(edgeW, sage_Wl, sage_Wr, gat_W, wcvt);

  float* xin = xa; float* xout = xb;
  const int gemm_blocks = (NN+63)/64;   // 313
  for (int i=0;i<3;i++){
    k_aggr<<<NN/4, 256, 0, stream>>>(xin, off, csr, agg);
    k_ngemm<true,false><<<gemm_blocks, 256, 0, stream>>>(
        agg, xin, wcvt + (size_t)(2+i)*4096, wcvt + (size_t)(5+i)*4096,
        sage_bl + (size_t)i*H, xout, nullptr, nullptr, nullptr, nullptr, NN);
    float* t = xin; xin = xout; xout = t;
  }

  // GAT: h = x@W (into agg) + per-node hs/hd scalars fused in epilogue
  k_ngemm<false,true><<<gemm_blocks, 256, 0, stream>>>(
      xin, nullptr, wcvt + (size_t)8*4096, nullptr,
      nullptr, agg, gat_asrc, gat_adst, hs, hd, NN);
  k_gat<<<NN/4, 256, 0, stream>>>(agg, hs, hd, off, csr, gat_b, xout);
  { float* t = xin; xin = xout; xout = t; }

  k_edge_mfma<<<NE/64, 256, 0, stream>>>(xout==xa?xb:xa, csr, dstA, eidA, wcvt,
      edgeb, edgeb + H, outW, outb, (float*)d_out);
}